// Round 12
// baseline (22555.331 us; speedup 1.0000x reference)
//
#include <hip/hip_runtime.h>
#include <stdint.h>

typedef short s8v __attribute__((ext_vector_type(8)));
typedef _Float16 h8v __attribute__((ext_vector_type(8)));
typedef float f4v __attribute__((ext_vector_type(4)));
typedef unsigned short u16;
typedef unsigned int u32;
typedef unsigned long long u64;

#define TT 800
#define BB 128
#define UU 64
#define ALP 73
#define DD 400

#define G_BATCH 32
#define N_CLUS 4
#define N_MEM 50
#define NTHREADS 256

// activation columns (f16 elements)
#define CX0 0
#define CX1 32
#define CWIN 64
#define CWINLO 160
#define CH1 256
#define CH2 672
#define CH3 1088
#define ACT_STRIDE 3072

#define NC1 17
#define NC2 30
#define NC3 43
#define NCO 39
#define NCA 13
#define F1 5
#define F2 8
#define F3 11
#define FA 4
#define FO 10

#define ACT_BYTES (32*ACT_STRIDE)          // 98304
#define H1LO_OFF ACT_BYTES                 // 28672
#define H1LO_STRIDE 896
#define RBUF_OFF (H1LO_OFF + 32*H1LO_STRIDE)   // 126976
#define ABK_OFF (RBUF_OFF + 16384)         // slot4 first 3840B
#define WINS_OFF (ABK_OFF + 3840)          // next 10240B (slots 5-7 area)
#define CHAR_OFF (RBUF_OFF + 32768)
#define LENS_OFF (CHAR_OFF + 2048)
#define BIASC_OFF (LENS_OFF + 128)
#define BCI_OFF (BIASC_OFF + 128)
#define BAS_OFF (BCI_OFF + 384)
#define BGS_OFF (BAS_OFF + 128)
#define LDS_TOTAL (BGS_OFF + 128)          // 162688

#define OFF_SIG ((size_t)BB*TT*20)
#define OFF_RHO ((size_t)BB*TT*60)
#define OFF_MU  ((size_t)BB*TT*80)
#define OFF_ES  ((size_t)BB*TT*120)

#define HBUF_U32 25600

#define MFMA16(A,B,C) __builtin_amdgcn_mfma_f32_16x16x32_f16(__builtin_bit_cast(h8v,(A)),__builtin_bit_cast(h8v,(B)),(C),0,0,0)

#define AST(p,v) __hip_atomic_store((p),(v),__ATOMIC_RELAXED,__HIP_MEMORY_SCOPE_AGENT)
#define ALD(p)   __hip_atomic_load((p),__ATOMIC_RELAXED,__HIP_MEMORY_SCOPE_AGENT)

__device__ __forceinline__ u16 f16b(float x) {
  _Float16 h = (_Float16)x;
  return __builtin_bit_cast(u16, h);
}
__device__ __forceinline__ float f2f(u16 h) {
  return (float)__builtin_bit_cast(_Float16, h);
}
__device__ __forceinline__ float sigm(float x) { return 1.f / (1.f + __expf(-x)); }
__device__ __forceinline__ float tanhe(float x) {
  float e = __expf(-2.f * fabsf(x));
  float r = (1.f - e) / (1.f + e);
  return (x < 0.f) ? -r : r;
}
__device__ __forceinline__ int imin(int a, int b) { return a < b ? a : b; }
__device__ __forceinline__ int lstm_row(int mem, int n, int r) {
  return (n*2 + (r>>3))*400 + mem*8 + (r&7);
}
__device__ __forceinline__ int out_orow(int rc) {
  if (rc < 20) return rc;
  if (rc < 60) return 60 + (rc-20);
  if (rc < 80) return 100 + (rc-60);
  if (rc < 120) return 20 + (rc-80);
  if (rc == 120) return 120;
  return -1;
}
// quad-XOR swizzle within a 256-float RBUF fragment: <=2-way banks everywhere
__device__ __forceinline__ int rbswz(int col, int row) {
  return col*16 + ((((row >> 2) ^ ((col >> 1) & 3)) << 2) | (row & 3));
}
__device__ __forceinline__ s8v gath(const float* W, int ld, int grow, int cb, int valid, int k0) {
  union { s8v v; u16 u[8]; } r;
  #pragma unroll
  for (int j = 0; j < 8; ++j) {
    int k = k0 + j;
    float x = 0.f;
    if (grow >= 0 && k < valid) x = W[(size_t)grow * ld + cb + k];
    r.u[j] = f16b(x);
  }
  return r.v;
}
__device__ __forceinline__ s8v gathlo(const float* W, int ld, int grow, int cb, int valid, int k0) {
  union { s8v v; u16 u[8]; } r;
  #pragma unroll
  for (int j = 0; j < 8; ++j) {
    int k = k0 + j;
    float x = 0.f;
    if (grow >= 0 && k < valid) x = W[(size_t)grow * ld + cb + k];
    u16 hi = f16b(x);
    r.u[j] = f16b(x - f2f(hi));
  }
  return r.v;
}

extern "C" __global__ __launch_bounds__(NTHREADS, 1)
void hwrnn(const float* __restrict__ xin, const int* __restrict__ chq,
           const int* __restrict__ lenq, const float* __restrict__ biasq,
           const float* __restrict__ Wih1, const float* __restrict__ Whh1,
           const float* __restrict__ bih1, const float* __restrict__ bhh1,
           const float* __restrict__ Wih2, const float* __restrict__ Whh2,
           const float* __restrict__ bih2, const float* __restrict__ bhh2,
           const float* __restrict__ Wih3, const float* __restrict__ Whh3,
           const float* __restrict__ bih3, const float* __restrict__ bhh3,
           const float* __restrict__ Wa, const float* __restrict__ ba,
           const float* __restrict__ Wg, const float* __restrict__ bg,
           float* __restrict__ dout, u32* __restrict__ barr,
           u32* __restrict__ h1ring, u32* __restrict__ h2g, u32* __restrict__ h3g,
           u32* __restrict__ h1glo)
{
  extern __shared__ __align__(16) char sm[];
  const int tid = threadIdx.x;
  const int wv = tid >> 6;
  const int ln = tid & 63;
  const int cl = blockIdx.x & 3;
  const int mem = blockIdx.x >> 2;
  const int B0 = cl * G_BATCH;

  const int arow = ln & 15;
  const int k0 = (ln >> 4) * 8;
  const int ahi = (ln >> 4) * 16;
  const int axor = (ln & 7) << 4;
  const int rb0 = arow * ACT_STRIDE;
  const int rb1 = (16 + arow) * ACT_STRIDE;
  const int hb0 = H1LO_OFF + arow * H1LO_STRIDE;
  const int hb1 = H1LO_OFF + (16 + arow) * H1LO_STRIDE;
  const f4v az = {0.f, 0.f, 0.f, 0.f};

  // ---- init ----
  for (int i = tid; i * 16 < RBUF_OFF; i += NTHREADS) *(f4v*)(sm + i*16) = az;
  for (int i = tid; i < 32*UU; i += NTHREADS) {
    int b = i >> 6, u = i & 63;
    ((unsigned char*)(sm + CHAR_OFF))[i] = (unsigned char)chq[(B0 + b)*UU + u];
  }
  if (tid < 32) {
    ((int*)(sm + LENS_OFF))[tid] = lenq[B0 + tid];
    ((float*)(sm + BIASC_OFF))[tid] = biasq[B0 + tid];
    ((float*)(sm + BAS_OFF))[tid] = (tid < 30) ? ba[tid] : 0.f;
    float v = 0.f;
    if (mem == 0) { int orow = out_orow(tid); if (orow >= 0) v = bg[orow]; }
    else if (mem >= 1 && mem <= 6 && tid < 16) {
      int orow = out_orow((mem+1)*16 + tid); if (orow >= 0) v = bg[orow];
    }
    ((float*)(sm + BGS_OFF))[tid] = v;
  }
  if (tid < 96) {
    int l = tid >> 5, r = tid & 31;
    int grow = lstm_row(mem, r >> 4, r & 15);
    const float* bi = (l == 0) ? bih1 : (l == 1) ? bih2 : bih3;
    const float* bh = (l == 0) ? bhh1 : (l == 1) ? bhh2 : bhh3;
    ((float*)(sm + BCI_OFF))[l*32 + r] = bi[grow] + bh[grow];
  }

  // ---- stationary weight fragments (f16, VGPR/AGPR-resident) ----
  s8v wf1[F1][2], wf2[F2][2], wf3[F3][2], wfa[FA][2], walo[FA][2], wfo[2][FO];
  #pragma unroll
  for (int i = 0; i < F1; ++i) {
    int c = wv + 4*i;
    #pragma unroll
    for (int n = 0; n < 2; ++n) {
      s8v v = {0,0,0,0,0,0,0,0};
      if (c < NC1) {
        int grow = lstm_row(mem, n, arow);
        if (c == 0)      v = gath(Wih1, 76, grow, 73, 3, k0);
        else if (c <= 3) v = gath(Wih1, 76, grow, (c-1)*32, imin(32, 73-(c-1)*32), k0);
        else             v = gath(Whh1, 400, grow, (c-4)*32, imin(32, 400-(c-4)*32), k0);
      }
      wf1[i][n] = v;
    }
  }
  #pragma unroll
  for (int i = 0; i < F2; ++i) {
    int c = wv + 4*i;
    #pragma unroll
    for (int n = 0; n < 2; ++n) {
      s8v v = {0,0,0,0,0,0,0,0};
      if (c < NC2) {
        int grow = lstm_row(mem, n, arow);
        if (c == 0)       v = gath(Wih2, 476, grow, 0, 3, k0);
        else if (c <= 13) v = gath(Wih2, 476, grow, 3+32*(c-1), imin(32, 400-32*(c-1)), k0);
        else if (c <= 16) v = gath(Wih2, 476, grow, 403+32*(c-14), imin(32, 73-32*(c-14)), k0);
        else              v = gath(Whh2, 400, grow, 32*(c-17), imin(32, 400-32*(c-17)), k0);
      }
      wf2[i][n] = v;
    }
  }
  #pragma unroll
  for (int i = 0; i < F3; ++i) {
    int c = wv + 4*i;
    #pragma unroll
    for (int n = 0; n < 2; ++n) {
      s8v v = {0,0,0,0,0,0,0,0};
      if (c < NC3) {
        int grow = lstm_row(mem, n, arow);
        if (c == 0)       v = gath(Wih3, 876, grow, 0, 3, k0);
        else if (c <= 13) v = gath(Wih3, 876, grow, 3+32*(c-1), imin(32, 400-32*(c-1)), k0);
        else if (c <= 26) v = gath(Wih3, 876, grow, 403+32*(c-14), imin(32, 400-32*(c-14)), k0);
        else if (c <= 29) v = gath(Wih3, 876, grow, 803+32*(c-27), imin(32, 73-32*(c-27)), k0);
        else              v = gath(Whh3, 400, grow, 32*(c-30), imin(32, 400-32*(c-30)), k0);
      }
      wf3[i][n] = v;
    }
  }
  #pragma unroll
  for (int i = 0; i < FA; ++i) {
    int c = wv + 4*i;
    #pragma unroll
    for (int n = 0; n < 2; ++n) {
      s8v v = {0,0,0,0,0,0,0,0}, vl = v;
      if (c < NCA) {
        int rr = n*16 + arow;
        int grow = (rr < 30) ? rr : -1;
        v  = gath  (Wa, 400, grow, 32*c, imin(32, 400-32*c), k0);
        vl = gathlo(Wa, 400, grow, 32*c, imin(32, 400-32*c), k0);
      }
      wfa[i][n] = v; walo[i][n] = vl;
    }
  }
  #pragma unroll
  for (int o = 0; o < 2; ++o) {
    #pragma unroll
    for (int i = 0; i < FO; ++i) {
      s8v v = {0,0,0,0,0,0,0,0};
      int c = wv + 4*i;
      bool have = (mem == 0) || (mem >= 1 && mem <= 6 && o == 0);
      if (have && c < NCO) {
        int ct = (mem == 0) ? o : (mem + 1);
        int grow = out_orow(ct*16 + arow);
        if (c <= 12)      v = gath(Wg, 1200, grow, 32*c, imin(32, 400-32*c), k0);
        else if (c <= 25) v = gath(Wg, 1200, grow, 400+32*(c-13), imin(32, 400-32*(c-13)), k0);
        else              v = gath(Wg, 1200, grow, 800+32*(c-26), imin(32, 400-32*(c-26)), k0);
      }
      wfo[o][i] = v;
    }
  }

  // ---- helpers ----
  auto LDA0 = [&](int cb2) -> s8v { return *(const s8v*)(sm + rb0 + ((cb2 + ahi) ^ axor)); };
  auto LDA1 = [&](int cb2) -> s8v { return *(const s8v*)(sm + rb1 + ((cb2 + ahi) ^ axor)); };
  auto LDL0 = [&](int cb2) -> s8v { return *(const s8v*)(sm + hb0 + ((cb2 + ahi) ^ axor)); };
  auto LDL1 = [&](int cb2) -> s8v { return *(const s8v*)(sm + hb1 + ((cb2 + ahi) ^ axor)); };
  // RBUF fragment store/load with quad-XOR swizzle (bank-conflict fix)
  auto WPART = [&](int slot, f4v a) {
    int col = ln & 15;
    int q = (ln >> 4) ^ ((col >> 1) & 3);
    *(f4v*)(sm + RBUF_OFF + (((slot*4 + wv)*256) + col*16 + q*4)*4) = a;
  };
  auto RBF = [&](int slot, int w, int col, int row) -> float {
    return ((float*)(sm + RBUF_OFF))[(slot*4 + w)*256 + rbswz(col, row)];
  };
  // OUT A-fragment from global rings (agent-coherent loads)
  auto RLD = [&](const u32* ring, int half) -> s8v {
    union { s8v v; u64 q[2]; } r;
    r.q[0] = ALD((const u64*)ring + ((size_t)(B0 + arow + 16*half)*DD + k0 >> 2));
    r.q[1] = ALD((const u64*)ring + ((size_t)(B0 + arow + 16*half)*DD + k0 + 4 >> 2));
    return r.v;
  };
  const int ub = tid >> 3, uu = tid & 7;
  auto LUPD = [&](int sb, int l, float& c, u32* hg, u32* hlo) {
    int mt = ub >> 4, rw = ub & 15;
    const float* bci = (const float*)(sm + BCI_OFF);
    float vi = bci[l*32 + uu], vf = bci[l*32 + 8 + uu];
    float vg = bci[l*32 + 16 + uu], vo = bci[l*32 + 24 + uu];
    #pragma unroll
    for (int w = 0; w < 4; ++w) {
      vi += RBF(sb + mt, w, uu, rw);
      vf += RBF(sb + mt, w, 8 + uu, rw);
      vg += RBF(sb + 2 + mt, w, uu, rw);
      vo += RBF(sb + 2 + mt, w, 8 + uu, rw);
    }
    c = sigm(vf)*c + sigm(vi)*tanhe(vg);
    float h = sigm(vo)*tanhe(c);
    u16 hb = f16b(h);
    float hl = h - f2f(hb);
    float ho = __shfl_xor(h, 1, 64);
    float hlo_o = __shfl_xor(hl, 1, 64);
    if (!(uu & 1)) {
      size_t gi = ((size_t)(B0 + ub)*DD + mem*8 + uu) >> 1;
      AST(hg + gi, (u32)hb | ((u32)f16b(ho) << 16));
      if (hlo) AST(hlo + gi, (u32)f16b(hl) | ((u32)f16b(hlo_o) << 16));
    }
  };
  // Bulk staging: issue ALL LLC loads into registers, then LDS writes.
  auto STAGEH = [&](const u32* hg, int cbase) {
    u64 va[7], vb[7];
    #pragma unroll
    for (int s = 0; s < 7; ++s) {
      int idx = tid + s*NTHREADS;
      if (idx < 1600) {
        int b = idx / 50, c16 = idx % 50;
        const u64* p = (const u64*)(hg + (((size_t)(B0 + b)*DD + c16*8) >> 1));
        va[s] = ALD(p); vb[s] = ALD(p + 1);
      }
    }
    #pragma unroll
    for (int s = 0; s < 7; ++s) {
      int idx = tid + s*NTHREADS;
      if (idx < 1600) {
        int b = idx / 50, c16 = idx % 50;
        int off = b*ACT_STRIDE + ((2*(cbase + c16*8)) ^ ((b & 7) << 4));
        *(u64*)(sm + off) = va[s];
        *(u64*)(sm + off + 8) = vb[s];
      }
    }
  };
  auto STAGEHLO = [&](const u32* hg) {
    u64 va[7], vb[7];
    #pragma unroll
    for (int s = 0; s < 7; ++s) {
      int idx = tid + s*NTHREADS;
      if (idx < 1600) {
        int b = idx / 50, c16 = idx % 50;
        const u64* p = (const u64*)(hg + (((size_t)(B0 + b)*DD + c16*8) >> 1));
        va[s] = ALD(p); vb[s] = ALD(p + 1);
      }
    }
    #pragma unroll
    for (int s = 0; s < 7; ++s) {
      int idx = tid + s*NTHREADS;
      if (idx < 1600) {
        int b = idx / 50, c16 = idx % 50;
        int off = H1LO_OFF + b*H1LO_STRIDE + ((16*c16) ^ ((b & 7) << 4));
        *(u64*)(sm + off) = va[s];
        *(u64*)(sm + off + 8) = vb[s];
      }
    }
  };
  // single atomic-counter barrier per cluster (one LLC line)
  u32* cA = barr + cl*64;
  auto ARRIVE = [&]() {
    asm volatile("s_waitcnt vmcnt(0)" ::: "memory");
    __syncthreads();
    if (tid == 0) __hip_atomic_fetch_add(cA, 1u, __ATOMIC_RELAXED, __HIP_MEMORY_SCOPE_AGENT);
  };
  auto WAITC = [&](u32 tgt) {
    if (tid == 0) {
      while (ALD(cA) < tgt) __builtin_amdgcn_s_sleep(1);
    }
    __syncthreads();
  };

  // ---- prologue: x(0) ----
  __syncthreads();
  if (tid < 96) {
    int b = tid/3, cc = tid%3;
    float x = xin[((size_t)(B0+b)*TT)*3 + cc];
    int off = b*ACT_STRIDE + ((2*(CX0 + cc)) ^ ((b&7)<<4));
    *(u16*)(sm + off) = f16b(x);
  }
  __syncthreads();

  float c1 = 0.f, c2 = 0.f, c3 = 0.f, kap0 = 0.f, kap1 = 0.f;

  for (int t = 0; t <= TT + 2; ++t) {
    const int pc = t & 1, pp = pc ^ 1;
    const int xc = pc ? CX1 : CX0;
    const int xp = pp ? CX1 : CX0;
    u32* ring_w = h1ring + (size_t)(t & 7) * HBUF_U32;

    // ======== G1(t) -> h1(t) publish; arrive ========
    if (t < TT) {
      f4v a1[4] = {az, az, az, az};
      #pragma unroll
      for (int i = 0; i < F1; ++i) {
        int c = wv + 4*i;
        if (c < NC1) {
          int cb = (c == 0) ? xc : (c <= 3) ? (CWIN + 32*(c-1)) : (CH1 + 32*(c-4));
          int cb2 = 2*cb;
          s8v x0 = LDA0(cb2), x1 = LDA1(cb2);
          a1[0] = MFMA16(x0, wf1[i][0], a1[0]);
          a1[1] = MFMA16(x1, wf1[i][0], a1[1]);
          a1[2] = MFMA16(x0, wf1[i][1], a1[2]);
          a1[3] = MFMA16(x1, wf1[i][1], a1[3]);
          if (c >= 1) {
            s8v l0, l1;
            if (c <= 3) { int lb2 = 2*(CWINLO + 32*(c-1)); l0 = LDA0(lb2); l1 = LDA1(lb2); }
            else        { int lb2 = 64*(c-4);              l0 = LDL0(lb2); l1 = LDL1(lb2); }
            a1[0] = MFMA16(l0, wf1[i][0], a1[0]);
            a1[1] = MFMA16(l1, wf1[i][0], a1[1]);
            a1[2] = MFMA16(l0, wf1[i][1], a1[2]);
            a1[3] = MFMA16(l1, wf1[i][1], a1[3]);
          }
        }
      }
      WPART(0, a1[0]); WPART(1, a1[1]); WPART(2, a1[2]); WPART(3, a1[3]);
    }
    __syncthreads();
    if (t < TT) LUPD(0, 0, c1, ring_w, h1glo + (size_t)pc * HBUF_U32);
    ARRIVE();

    // ======== barrier shadow: OUT(t-3) entirely from global rings ========
    if (t >= 3 && mem <= 6) {
      const u32* r1 = h1ring + (size_t)((t + 5) & 7) * HBUF_U32;   // h1(t-3)
      const u32* r2 = h2g   + (size_t)((t + 1) & 3) * HBUF_U32;    // h2(t-3)
      const u32* r3 = h3g   + (size_t)((t + 1) & 3) * HBUF_U32;    // h3(t-3)
      // bulk-issue ALL fragment loads (kills the 10-deep serial LLC chain)
      s8v xf0[FO], xf1[FO];
      #pragma unroll
      for (int i = 0; i < FO; ++i) {
        int c = wv + 4*i;
        if (c < NCO) {
          const u32* rp = (c <= 12) ? (r1 + (size_t)c * 16)
                        : (c <= 25) ? (r2 + (size_t)(c - 13) * 16)
                        :             (r3 + (size_t)(c - 26) * 16);
          xf0[i] = RLD(rp, 0); xf1[i] = RLD(rp, 1);
        }
      }
      f4v ao[4] = {az, az, az, az};
      #pragma unroll
      for (int i = 0; i < FO; ++i) {
        int c = wv + 4*i;
        if (c < NCO) {
          ao[0] = MFMA16(xf0[i], wfo[0][i], ao[0]);
          ao[1] = MFMA16(xf1[i], wfo[0][i], ao[1]);
          if (mem == 0) {
            ao[2] = MFMA16(xf0[i], wfo[1][i], ao[2]);
            ao[3] = MFMA16(xf1[i], wfo[1][i], ao[3]);
          }
        }
      }
      WPART(4, ao[0]); WPART(5, ao[1]);
      if (mem == 0) { WPART(6, ao[2]); WPART(7, ao[3]); }
      __syncthreads();
      const float* bgs = (const float*)(sm + BGS_OFF);
      const float* bcv = (const float*)(sm + BIASC_OFF);
      int tt = t - 3;
      auto OSUM = [&](int rl, int b) -> float {
        int slot = 4 + ((mem == 0) ? ((rl >> 4)*2) : 0) + (b >> 4);
        float s = bgs[rl];
        #pragma unroll
        for (int w = 0; w < 4; ++w) s += RBF(slot, w, rl & 15, b & 15);
        return s;
      };
      if (mem == 0) {
        if (tid < 32) {
          int b = tid;
          float sc = 1.f + bcv[b];
          float pv[20]; float mx = -3e38f;
          #pragma unroll
          for (int r = 0; r < 20; ++r) { pv[r] = OSUM(r, b) * sc; mx = fmaxf(mx, pv[r]); }
          float den = 0.f;
          #pragma unroll
          for (int r = 0; r < 20; ++r) { pv[r] = __expf(pv[r] - mx); den += pv[r]; }
          float inv = 1.f / den;
          size_t ob = ((size_t)(B0 + b)*TT + tt);
          #pragma unroll
          for (int r = 0; r < 20; ++r) dout[ob*20 + r] = pv[r] * inv;
        }
        for (int idx = tid; idx < 12*32; idx += NTHREADS) {
          int rl = 20 + (idx >> 5), b = idx & 31;
          float v = OSUM(rl, b);
          size_t ob = ((size_t)(B0 + b)*TT + tt);
          dout[OFF_SIG + ob*40 + (rl - 20)] = __expf(v - bcv[b]);
        }
      } else {
        int RB = (mem + 1) * 16;
        for (int idx = tid; idx < 512; idx += NTHREADS) {
          int rl = idx >> 5, b = idx & 31;
          int rc = RB + rl;
          float v = OSUM(rl, b);
          size_t ob = ((size_t)(B0 + b)*TT + tt);
          if (rc < 60)        dout[OFF_SIG + ob*40 + (rc - 20)] = __expf(v - bcv[b]);
          else if (rc < 80)   dout[OFF_RHO + ob*20 + (rc - 60)] = tanhe(v);
          else if (rc < 120)  dout[OFF_MU  + ob*40 + (rc - 80)] = v;
          else if (rc == 120) dout[OFF_ES + ob] = sigm(v);
        }
      }
    }

    // ======== THE one barrier ========
    WAITC((u32)(t + 1) * N_MEM);

    // ---- qA: stage h3(t-2) -> CH3 and h2(t-1) -> CH2 ----
    if (t >= 2 && t <= TT) STAGEH(h3g + (size_t)((t + 2) & 3) * HBUF_U32, CH3);
    if (t >= 1 && t <= TT) STAGEH(h2g + (size_t)((t + 3) & 3) * HBUF_U32, CH2);
    __syncthreads();

    // ---- qB: G3(t-1) MFMA (slots 4-7) ; G2 head into regs ----
    f4v a2[4] = {az, az, az, az};
    if (t >= 1 && t <= TT) {
      f4v a3[4] = {az, az, az, az};
      #pragma unroll
      for (int i = 0; i < F3; ++i) {
        int c = wv + 4*i;
        if (c < NC3) {
          int cb = (c == 0) ? xp
                 : (c <= 13) ? (CH1 + 32*(c-1))
                 : (c <= 26) ? (CH2 + 32*(c-14))
                 : (c <= 29) ? (CWIN + 32*(c-27))
                 : (CH3 + 32*(c-30));
          int cb2 = 2*cb;
          s8v x0 = LDA0(cb2), x1 = LDA1(cb2);
          a3[0] = MFMA16(x0, wf3[i][0], a3[0]);
          a3[1] = MFMA16(x1, wf3[i][0], a3[1]);
          a3[2] = MFMA16(x0, wf3[i][1], a3[2]);
          a3[3] = MFMA16(x1, wf3[i][1], a3[3]);
          if ((c >= 1 && c <= 13) || (c >= 27 && c <= 29)) {
            s8v l0, l1;
            if (c <= 13) { int lb2 = 64*(c-1);               l0 = LDL0(lb2); l1 = LDL1(lb2); }
            else         { int lb2 = 2*(CWINLO + 32*(c-27)); l0 = LDA0(lb2); l1 = LDA1(lb2); }
            a3[0] = MFMA16(l0, wf3[i][0], a3[0]);
            a3[1] = MFMA16(l1, wf3[i][0], a3[1]);
            a3[2] = MFMA16(l0, wf3[i][1], a3[2]);
            a3[3] = MFMA16(l1, wf3[i][1], a3[3]);
          }
        }
      }
      WPART(4, a3[0]); WPART(5, a3[1]); WPART(6, a3[2]); WPART(7, a3[3]);
    }
    if (t < TT) {
      #pragma unroll
      for (int i = 0; i < F2; ++i) {
        int c = wv + 4*i;
        if (c < NC2 && (c == 0 || c >= 17)) {
          int cb = (c == 0) ? xc : (CH2 + 32*(c-17));
          int cb2 = 2*cb;
          s8v x0 = LDA0(cb2), x1 = LDA1(cb2);
          a2[0] = MFMA16(x0, wf2[i][0], a2[0]);
          a2[1] = MFMA16(x1, wf2[i][0], a2[1]);
          a2[2] = MFMA16(x0, wf2[i][1], a2[2]);
          a2[3] = MFMA16(x1, wf2[i][1], a2[3]);
        }
      }
    }
    __syncthreads();

    // ---- qC: stage h1(t)+lo -> CH1/H1LO; stage x(t+1) ----
    if (t < TT) { STAGEH(ring_w, CH1); STAGEHLO(h1glo + (size_t)pc * HBUF_U32); }
    if (t + 1 < TT && tid < 96) {
      int b = tid/3, cc = tid%3;
      float x = xin[((size_t)(B0+b)*TT + (t+1))*3 + cc];
      int off = b*ACT_STRIDE + ((2*(xp + cc)) ^ ((b&7)<<4));
      *(u16*)(sm + off) = f16b(x);
    }
    __syncthreads();

    // ---- qD: attention MFMA (slots 0-3) ; LUPD h3(t-1) -> publish ----
    if (t < TT) {
      f4v aa[4] = {az, az, az, az};
      #pragma unroll
      for (int i = 0; i < FA; ++i) {
        int c = wv + 4*i;
        if (c < NCA) {
          int cb2 = 2*(CH1 + 32*c);
          int lb2 = 64*c;
          s8v x0 = LDA0(cb2), x1 = LDA1(cb2);
          s8v l0 = LDL0(lb2), l1 = LDL1(lb2);
          aa[0] = MFMA16(x0, wfa[i][0], aa[0]);
          aa[1] = MFMA16(x1, wfa[i][0], aa[1]);
          aa[2] = MFMA16(x0, wfa[i][1], aa[2]);
          aa[3] = MFMA16(x1, wfa[i][1], aa[3]);
          aa[0] = MFMA16(l0, wfa[i][0], aa[0]);
          aa[1] = MFMA16(l1, wfa[i][0], aa[1]);
          aa[2] = MFMA16(l0, wfa[i][1], aa[2]);
          aa[3] = MFMA16(l1, wfa[i][1], aa[3]);
          aa[0] = MFMA16(x0, walo[i][0], aa[0]);
          aa[1] = MFMA16(x1, walo[i][0], aa[1]);
          aa[2] = MFMA16(x0, walo[i][1], aa[2]);
          aa[3] = MFMA16(x1, walo[i][1], aa[3]);
        }
      }
      WPART(0, aa[0]); WPART(1, aa[1]); WPART(2, aa[2]); WPART(3, aa[3]);
    }
    if (t >= 1 && t <= TT) LUPD(4, 2, c3, h3g + (size_t)((t + 3) & 3) * HBUF_U32, nullptr);
    __syncthreads();

    if (t < TT) {
      // ---- qE: zero wins + alpha/beta/kappa ----
      float* wins = (float*)(sm + WINS_OFF);
      for (int i = tid; i < 32*80; i += NTHREADS) wins[i] = 0.f;
      float* abk = (float*)(sm + ABK_OFF);
      const float* bas = (const float*)(sm + BAS_OFF);
      #pragma unroll
      for (int half = 0; half < 2; ++half) {
        int idx = tid + half*NTHREADS;
        if (idx < 320) {
          int b = idx & 31, j = idx >> 5;
          float ah = bas[j], bh = bas[10+j], kh = bas[20+j];
          #pragma unroll
          for (int w = 0; w < 4; ++w) {
            ah += RBF(0 + (b>>4), w, j, b & 15);
            if (j < 6) bh += RBF(0 + (b>>4), w, 10 + j, b & 15);
            else       bh += RBF(2 + (b>>4), w, j - 6, b & 15);
            kh += RBF(2 + (b>>4), w, 4 + j, b & 15);
          }
          float& kp = half ? kap1 : kap0;
          kp += __expf(kh);
          abk[0*320 + b*10 + j] = __expf(ah);
          abk[1*320 + b*10 + j] = __expf(bh);
          abk[2*320 + b*10 + j] = kp;
        }
      }
      __syncthreads();

      // ---- qF: phi + one-hot scatter ----
      const unsigned char* chs = (const unsigned char*)(sm + CHAR_OFF);
      const int* lns = (const int*)(sm + LENS_OFF);
      for (int idx = tid; idx < 32*64; idx += NTHREADS) {
        int b = idx >> 6, u = idx & 63;
        if (u < lns[b]) {
          float ph = 0.f, fu = (float)u;
          #pragma unroll
          for (int j = 0; j < 10; ++j) {
            float d = abk[2*320 + b*10 + j] - fu;
            ph += abk[0*320 + b*10 + j] * __expf(-abk[1*320 + b*10 + j]*d*d);
          }
          atomicAdd(&wins[b*80 + (int)chs[b*64 + u]], ph);
        }
      }
      __syncthreads();

      // ---- qG: window -> act (hi + lo) ----
      for (int idx = tid; idx < 32*96; idx += NTHREADS) {
        int b = idx / 96, cc = idx % 96;
        float v = (cc < ALP) ? wins[b*80 + cc] : 0.f;
        u16 hi = f16b(v);
        u16 lo = f16b(v - f2f(hi));
        int sw = (b&7) << 4;
        *(u16*)(sm + b*ACT_STRIDE + ((2*(CWIN + cc)) ^ sw)) = hi;
        *(u16*)(sm + b*ACT_STRIDE + ((2*(CWINLO + cc)) ^ sw)) = lo;
      }
      __syncthreads();

      // ---- qH: G2 tail: h1(t)+lo, win(t)+lo ----
      #pragma unroll
      for (int i = 0; i < F2; ++i) {
        int c = wv + 4*i;
        if (c >= 1 && c <= 16) {
          int cb = (c <= 13) ? (CH1 + 32*(c-1)) : (CWIN + 32*(c-14));
          int cb2 = 2*cb;
          s8v x0 = LDA0(cb2), x1 = LDA1(cb2);
          a2[0] = MFMA16(x0, wf2[i][0], a2[0]);
          a2[1] = MFMA16(x1, wf2[i][0], a2[1]);
          a2[2] = MFMA16(x0, wf2[i][1], a2[2]);
          a2[3] = MFMA16(x1, wf2[i][1], a2[3]);
          s8v l0, l1;
          if (c <= 13) { int lb2 = 64*(c-1);               l0 = LDL0(lb2); l1 = LDL1(lb2); }
          else         { int lb2 = 2*(CWINLO + 32*(c-14)); l0 = LDA0(lb2); l1 = LDA1(lb2); }
          a2[0] = MFMA16(l0, wf2[i][0], a2[0]);
          a2[1] = MFMA16(l1, wf2[i][0], a2[1]);
          a2[2] = MFMA16(l0, wf2[i][1], a2[2]);
          a2[3] = MFMA16(l1, wf2[i][1], a2[3]);
        }
      }
      WPART(0, a2[0]); WPART(1, a2[1]); WPART(2, a2[2]); WPART(3, a2[3]);
      __syncthreads();

      // ---- qI: h2(t) -> publish ----
      LUPD(0, 1, c2, h2g + (size_t)(t & 3) * HBUF_U32, nullptr);
    }
  }
}

extern "C" void kernel_launch(void* const* d_in, const int* in_sizes, int n_in,
                              void* d_out, int out_size, void* d_ws, size_t ws_size,
                              hipStream_t stream) {
  (void)in_sizes; (void)n_in; (void)out_size; (void)ws_size;
  const float* xin  = (const float*)d_in[0];
  const int*   chq  = (const int*)d_in[1];
  const int*   lnq  = (const int*)d_in[2];
  const float* bq   = (const float*)d_in[3];
  const float* Wih1 = (const float*)d_in[4];
  const float* Whh1 = (const float*)d_in[5];
  const float* bih1 = (const float*)d_in[6];
  const float* bhh1 = (const float*)d_in[7];
  const float* Wih2 = (const float*)d_in[8];
  const float* Whh2 = (const float*)d_in[9];
  const float* bih2 = (const float*)d_in[10];
  const float* bhh2 = (const float*)d_in[11];
  const float* Wih3 = (const float*)d_in[12];
  const float* Whh3 = (const float*)d_in[13];
  const float* bih3 = (const float*)d_in[14];
  const float* bhh3 = (const float*)d_in[15];
  const float* Wa   = (const float*)d_in[16];
  const float* ba   = (const float*)d_in[17];
  const float* Wg   = (const float*)d_in[18];
  const float* bg   = (const float*)d_in[19];
  float* dout = (float*)d_out;
  char* ws = (char*)d_ws;
  u32* barr   = (u32*)ws;
  u32* h1ring = (u32*)(ws + 16384);                // 8 x 102400 B
  u32* h2g    = (u32*)(ws + 16384 + 819200);       // 4 x 102400 B
  u32* h3g    = (u32*)(ws + 16384 + 1228800);      // 4 x 102400 B
  u32* h1glo  = (u32*)(ws + 16384 + 1638400);      // 2 x 102400 B

  hipMemsetAsync(ws, 0, 16384, stream);
  hipFuncSetAttribute(reinterpret_cast<const void*>(hwrnn),
                      hipFuncAttributeMaxDynamicSharedMemorySize, LDS_TOTAL);
  hipLaunchKernelGGL(hwrnn, dim3(N_CLUS * N_MEM), dim3(NTHREADS), LDS_TOTAL, stream,
                     xin, chq, lnq, bq, Wih1, Whh1, bih1, bhh1, Wih2, Whh2, bih2, bhh2,
                     Wih3, Whh3, bih3, bhh3, Wa, ba, Wg, bg, dout, barr,
                     h1ring, h2g, h3g, h1glo);
}

// Round 13
// 18714.391 us; speedup vs baseline: 1.2052x; 1.2052x over previous
//
#include <hip/hip_runtime.h>
#include <stdint.h>

typedef short s8v __attribute__((ext_vector_type(8)));
typedef _Float16 h8v __attribute__((ext_vector_type(8)));
typedef float f4v __attribute__((ext_vector_type(4)));
typedef unsigned short u16;
typedef unsigned int u32;
typedef unsigned long long u64;

#define TT 800
#define BB 128
#define UU 64
#define ALP 73
#define DD 400

#define G_BATCH 32
#define N_CLUS 4
#define N_MEM 50
#define NTHREADS 256

// activation columns (f16 elements)
#define CX0 0
#define CX1 32
#define CWIN 64
#define CWINLO 160
#define CH1 256
#define CH2 672
#define CH3 1088
#define ACT_STRIDE 3072

#define NC1 17
#define NC2 30
#define NC3 43
#define NCO 39
#define NCA 13
#define F1 5
#define F2 8
#define F3 11
#define FA 4
#define FO 10

#define ACT_BYTES (32*ACT_STRIDE)          // 98304
#define H1LO_OFF ACT_BYTES                 // 28672
#define H1LO_STRIDE 896
#define RBUF_OFF (H1LO_OFF + 32*H1LO_STRIDE)   // 126976
#define ABK_OFF (RBUF_OFF + 16384)         // slot4 first 3840B
#define WINS_OFF (ABK_OFF + 3840)          // next 10240B (slots 5-7 area)
#define CHAR_OFF (RBUF_OFF + 32768)
#define LENS_OFF (CHAR_OFF + 2048)
#define BIASC_OFF (LENS_OFF + 128)
#define BCI_OFF (BIASC_OFF + 128)
#define BAS_OFF (BCI_OFF + 384)
#define BGS_OFF (BAS_OFF + 128)
#define LDS_TOTAL (BGS_OFF + 128)          // 162688

#define OFF_SIG ((size_t)BB*TT*20)
#define OFF_RHO ((size_t)BB*TT*60)
#define OFF_MU  ((size_t)BB*TT*80)
#define OFF_ES  ((size_t)BB*TT*120)

#define HBUF_U32 25600

#define MFMA16(A,B,C) __builtin_amdgcn_mfma_f32_16x16x32_f16(__builtin_bit_cast(h8v,(A)),__builtin_bit_cast(h8v,(B)),(C),0,0,0)

#define AST(p,v) __hip_atomic_store((p),(v),__ATOMIC_RELAXED,__HIP_MEMORY_SCOPE_AGENT)
#define ALD(p)   __hip_atomic_load((p),__ATOMIC_RELAXED,__HIP_MEMORY_SCOPE_AGENT)

__device__ __forceinline__ u16 f16b(float x) {
  _Float16 h = (_Float16)x;
  return __builtin_bit_cast(u16, h);
}
__device__ __forceinline__ float f2f(u16 h) {
  return (float)__builtin_bit_cast(_Float16, h);
}
__device__ __forceinline__ float sigm(float x) { return 1.f / (1.f + __expf(-x)); }
__device__ __forceinline__ float tanhe(float x) {
  float e = __expf(-2.f * fabsf(x));
  float r = (1.f - e) / (1.f + e);
  return (x < 0.f) ? -r : r;
}
__device__ __forceinline__ int imin(int a, int b) { return a < b ? a : b; }
__device__ __forceinline__ int lstm_row(int mem, int n, int r) {
  return (n*2 + (r>>3))*400 + mem*8 + (r&7);
}
__device__ __forceinline__ int out_orow(int rc) {
  if (rc < 20) return rc;
  if (rc < 60) return 60 + (rc-20);
  if (rc < 80) return 100 + (rc-60);
  if (rc < 120) return 20 + (rc-80);
  if (rc == 120) return 120;
  return -1;
}
// quad-XOR swizzle within a 256-float RBUF fragment: <=2-way banks everywhere
__device__ __forceinline__ int rbswz(int col, int row) {
  return col*16 + ((((row >> 2) ^ ((col >> 1) & 3)) << 2) | (row & 3));
}
__device__ __forceinline__ s8v gath(const float* W, int ld, int grow, int cb, int valid, int k0) {
  union { s8v v; u16 u[8]; } r;
  #pragma unroll
  for (int j = 0; j < 8; ++j) {
    int k = k0 + j;
    float x = 0.f;
    if (grow >= 0 && k < valid) x = W[(size_t)grow * ld + cb + k];
    r.u[j] = f16b(x);
  }
  return r.v;
}
__device__ __forceinline__ s8v gathlo(const float* W, int ld, int grow, int cb, int valid, int k0) {
  union { s8v v; u16 u[8]; } r;
  #pragma unroll
  for (int j = 0; j < 8; ++j) {
    int k = k0 + j;
    float x = 0.f;
    if (grow >= 0 && k < valid) x = W[(size_t)grow * ld + cb + k];
    u16 hi = f16b(x);
    r.u[j] = f16b(x - f2f(hi));
  }
  return r.v;
}

extern "C" __global__ __launch_bounds__(NTHREADS, 1)
void hwrnn(const float* __restrict__ xin, const int* __restrict__ chq,
           const int* __restrict__ lenq, const float* __restrict__ biasq,
           const float* __restrict__ Wih1, const float* __restrict__ Whh1,
           const float* __restrict__ bih1, const float* __restrict__ bhh1,
           const float* __restrict__ Wih2, const float* __restrict__ Whh2,
           const float* __restrict__ bih2, const float* __restrict__ bhh2,
           const float* __restrict__ Wih3, const float* __restrict__ Whh3,
           const float* __restrict__ bih3, const float* __restrict__ bhh3,
           const float* __restrict__ Wa, const float* __restrict__ ba,
           const float* __restrict__ Wg, const float* __restrict__ bg,
           float* __restrict__ dout, u32* __restrict__ barr,
           u32* __restrict__ h1ring, u32* __restrict__ h2g, u32* __restrict__ h3g,
           u32* __restrict__ h1glo)
{
  extern __shared__ __align__(16) char sm[];
  const int tid = threadIdx.x;
  const int wv = tid >> 6;
  const int ln = tid & 63;
  const int cl = blockIdx.x & 3;
  const int mem = blockIdx.x >> 2;
  const int B0 = cl * G_BATCH;

  const int arow = ln & 15;
  const int k0 = (ln >> 4) * 8;
  const int ahi = (ln >> 4) * 16;
  const int axor = (ln & 7) << 4;
  const int rb0 = arow * ACT_STRIDE;
  const int rb1 = (16 + arow) * ACT_STRIDE;
  const int hb0 = H1LO_OFF + arow * H1LO_STRIDE;
  const int hb1 = H1LO_OFF + (16 + arow) * H1LO_STRIDE;
  const f4v az = {0.f, 0.f, 0.f, 0.f};

  // ---- init ----
  for (int i = tid; i * 16 < RBUF_OFF; i += NTHREADS) *(f4v*)(sm + i*16) = az;
  for (int i = tid; i < 32*UU; i += NTHREADS) {
    int b = i >> 6, u = i & 63;
    ((unsigned char*)(sm + CHAR_OFF))[i] = (unsigned char)chq[(B0 + b)*UU + u];
  }
  if (tid < 32) {
    ((int*)(sm + LENS_OFF))[tid] = lenq[B0 + tid];
    ((float*)(sm + BIASC_OFF))[tid] = biasq[B0 + tid];
    ((float*)(sm + BAS_OFF))[tid] = (tid < 30) ? ba[tid] : 0.f;
    float v = 0.f;
    if (mem == 0) { int orow = out_orow(tid); if (orow >= 0) v = bg[orow]; }
    else if (mem >= 1 && mem <= 6 && tid < 16) {
      int orow = out_orow((mem+1)*16 + tid); if (orow >= 0) v = bg[orow];
    }
    ((float*)(sm + BGS_OFF))[tid] = v;
  }
  if (tid < 96) {
    int l = tid >> 5, r = tid & 31;
    int grow = lstm_row(mem, r >> 4, r & 15);
    const float* bi = (l == 0) ? bih1 : (l == 1) ? bih2 : bih3;
    const float* bh = (l == 0) ? bhh1 : (l == 1) ? bhh2 : bhh3;
    ((float*)(sm + BCI_OFF))[l*32 + r] = bi[grow] + bh[grow];
  }

  // ---- stationary weight fragments (f16, VGPR/AGPR-resident) ----
  s8v wf1[F1][2], wf2[F2][2], wf3[F3][2], wfa[FA][2], walo[FA][2], wfo[2][FO];
  #pragma unroll
  for (int i = 0; i < F1; ++i) {
    int c = wv + 4*i;
    #pragma unroll
    for (int n = 0; n < 2; ++n) {
      s8v v = {0,0,0,0,0,0,0,0};
      if (c < NC1) {
        int grow = lstm_row(mem, n, arow);
        if (c == 0)      v = gath(Wih1, 76, grow, 73, 3, k0);
        else if (c <= 3) v = gath(Wih1, 76, grow, (c-1)*32, imin(32, 73-(c-1)*32), k0);
        else             v = gath(Whh1, 400, grow, (c-4)*32, imin(32, 400-(c-4)*32), k0);
      }
      wf1[i][n] = v;
    }
  }
  #pragma unroll
  for (int i = 0; i < F2; ++i) {
    int c = wv + 4*i;
    #pragma unroll
    for (int n = 0; n < 2; ++n) {
      s8v v = {0,0,0,0,0,0,0,0};
      if (c < NC2) {
        int grow = lstm_row(mem, n, arow);
        if (c == 0)       v = gath(Wih2, 476, grow, 0, 3, k0);
        else if (c <= 13) v = gath(Wih2, 476, grow, 3+32*(c-1), imin(32, 400-32*(c-1)), k0);
        else if (c <= 16) v = gath(Wih2, 476, grow, 403+32*(c-14), imin(32, 73-32*(c-14)), k0);
        else              v = gath(Whh2, 400, grow, 32*(c-17), imin(32, 400-32*(c-17)), k0);
      }
      wf2[i][n] = v;
    }
  }
  #pragma unroll
  for (int i = 0; i < F3; ++i) {
    int c = wv + 4*i;
    #pragma unroll
    for (int n = 0; n < 2; ++n) {
      s8v v = {0,0,0,0,0,0,0,0};
      if (c < NC3) {
        int grow = lstm_row(mem, n, arow);
        if (c == 0)       v = gath(Wih3, 876, grow, 0, 3, k0);
        else if (c <= 13) v = gath(Wih3, 876, grow, 3+32*(c-1), imin(32, 400-32*(c-1)), k0);
        else if (c <= 26) v = gath(Wih3, 876, grow, 403+32*(c-14), imin(32, 400-32*(c-14)), k0);
        else if (c <= 29) v = gath(Wih3, 876, grow, 803+32*(c-27), imin(32, 73-32*(c-27)), k0);
        else              v = gath(Whh3, 400, grow, 32*(c-30), imin(32, 400-32*(c-30)), k0);
      }
      wf3[i][n] = v;
    }
  }
  #pragma unroll
  for (int i = 0; i < FA; ++i) {
    int c = wv + 4*i;
    #pragma unroll
    for (int n = 0; n < 2; ++n) {
      s8v v = {0,0,0,0,0,0,0,0}, vl = v;
      if (c < NCA) {
        int rr = n*16 + arow;
        int grow = (rr < 30) ? rr : -1;
        v  = gath  (Wa, 400, grow, 32*c, imin(32, 400-32*c), k0);
        vl = gathlo(Wa, 400, grow, 32*c, imin(32, 400-32*c), k0);
      }
      wfa[i][n] = v; walo[i][n] = vl;
    }
  }
  #pragma unroll
  for (int o = 0; o < 2; ++o) {
    #pragma unroll
    for (int i = 0; i < FO; ++i) {
      s8v v = {0,0,0,0,0,0,0,0};
      int c = wv + 4*i;
      bool have = (mem == 0) || (mem >= 1 && mem <= 6 && o == 0);
      if (have && c < NCO) {
        int ct = (mem == 0) ? o : (mem + 1);
        int grow = out_orow(ct*16 + arow);
        if (c <= 12)      v = gath(Wg, 1200, grow, 32*c, imin(32, 400-32*c), k0);
        else if (c <= 25) v = gath(Wg, 1200, grow, 400+32*(c-13), imin(32, 400-32*(c-13)), k0);
        else              v = gath(Wg, 1200, grow, 800+32*(c-26), imin(32, 400-32*(c-26)), k0);
      }
      wfo[o][i] = v;
    }
  }

  // ---- helpers ----
  auto LDA0 = [&](int cb2) -> s8v { return *(const s8v*)(sm + rb0 + ((cb2 + ahi) ^ axor)); };
  auto LDA1 = [&](int cb2) -> s8v { return *(const s8v*)(sm + rb1 + ((cb2 + ahi) ^ axor)); };
  auto LDL0 = [&](int cb2) -> s8v { return *(const s8v*)(sm + hb0 + ((cb2 + ahi) ^ axor)); };
  auto LDL1 = [&](int cb2) -> s8v { return *(const s8v*)(sm + hb1 + ((cb2 + ahi) ^ axor)); };
  // RBUF fragment store/load with quad-XOR swizzle (bank-conflict fix)
  auto WPART = [&](int slot, f4v a) {
    int col = ln & 15;
    int q = (ln >> 4) ^ ((col >> 1) & 3);
    *(f4v*)(sm + RBUF_OFF + (((slot*4 + wv)*256) + col*16 + q*4)*4) = a;
  };
  auto RBF = [&](int slot, int w, int col, int row) -> float {
    return ((float*)(sm + RBUF_OFF))[(slot*4 + w)*256 + rbswz(col, row)];
  };
  // OUT A-fragment from global rings (agent-coherent loads)
  auto RLD = [&](const u32* ring, int half) -> s8v {
    union { s8v v; u64 q[2]; } r;
    r.q[0] = ALD((const u64*)ring + ((size_t)(B0 + arow + 16*half)*DD + k0 >> 2));
    r.q[1] = ALD((const u64*)ring + ((size_t)(B0 + arow + 16*half)*DD + k0 + 4 >> 2));
    return r.v;
  };
  const int ub = tid >> 3, uu = tid & 7;
  auto LUPD = [&](int sb, int l, float& c, u32* hg, u32* hlo) {
    int mt = ub >> 4, rw = ub & 15;
    const float* bci = (const float*)(sm + BCI_OFF);
    float vi = bci[l*32 + uu], vf = bci[l*32 + 8 + uu];
    float vg = bci[l*32 + 16 + uu], vo = bci[l*32 + 24 + uu];
    #pragma unroll
    for (int w = 0; w < 4; ++w) {
      vi += RBF(sb + mt, w, uu, rw);
      vf += RBF(sb + mt, w, 8 + uu, rw);
      vg += RBF(sb + 2 + mt, w, uu, rw);
      vo += RBF(sb + 2 + mt, w, 8 + uu, rw);
    }
    c = sigm(vf)*c + sigm(vi)*tanhe(vg);
    float h = sigm(vo)*tanhe(c);
    u16 hb = f16b(h);
    float hl = h - f2f(hb);
    float ho = __shfl_xor(h, 1, 64);
    float hlo_o = __shfl_xor(hl, 1, 64);
    if (!(uu & 1)) {
      size_t gi = ((size_t)(B0 + ub)*DD + mem*8 + uu) >> 1;
      AST(hg + gi, (u32)hb | ((u32)f16b(ho) << 16));
      if (hlo) AST(hlo + gi, (u32)f16b(hl) | ((u32)f16b(hlo_o) << 16));
    }
  };
  // Bulk staging: issue ALL LLC loads into registers, then LDS writes.
  auto STAGEH = [&](const u32* hg, int cbase) {
    u64 va[7], vb[7];
    #pragma unroll
    for (int s = 0; s < 7; ++s) {
      int idx = tid + s*NTHREADS;
      if (idx < 1600) {
        int b = idx / 50, c16 = idx % 50;
        const u64* p = (const u64*)(hg + (((size_t)(B0 + b)*DD + c16*8) >> 1));
        va[s] = ALD(p); vb[s] = ALD(p + 1);
      }
    }
    #pragma unroll
    for (int s = 0; s < 7; ++s) {
      int idx = tid + s*NTHREADS;
      if (idx < 1600) {
        int b = idx / 50, c16 = idx % 50;
        int off = b*ACT_STRIDE + ((2*(cbase + c16*8)) ^ ((b & 7) << 4));
        *(u64*)(sm + off) = va[s];
        *(u64*)(sm + off + 8) = vb[s];
      }
    }
  };
  auto STAGEHLO = [&](const u32* hg) {
    u64 va[7], vb[7];
    #pragma unroll
    for (int s = 0; s < 7; ++s) {
      int idx = tid + s*NTHREADS;
      if (idx < 1600) {
        int b = idx / 50, c16 = idx % 50;
        const u64* p = (const u64*)(hg + (((size_t)(B0 + b)*DD + c16*8) >> 1));
        va[s] = ALD(p); vb[s] = ALD(p + 1);
      }
    }
    #pragma unroll
    for (int s = 0; s < 7; ++s) {
      int idx = tid + s*NTHREADS;
      if (idx < 1600) {
        int b = idx / 50, c16 = idx % 50;
        int off = H1LO_OFF + b*H1LO_STRIDE + ((16*c16) ^ ((b & 7) << 4));
        *(u64*)(sm + off) = va[s];
        *(u64*)(sm + off + 8) = vb[s];
      }
    }
  };
  // single atomic-counter barrier per cluster (one LLC line)
  u32* cA = barr + cl*64;
  auto ARRIVE = [&]() {
    asm volatile("s_waitcnt vmcnt(0)" ::: "memory");
    __syncthreads();
    if (tid == 0) __hip_atomic_fetch_add(cA, 1u, __ATOMIC_RELAXED, __HIP_MEMORY_SCOPE_AGENT);
  };
  auto WAITC = [&](u32 tgt) {
    if (tid == 0) {
      while (ALD(cA) < tgt) __builtin_amdgcn_s_sleep(1);
    }
    __syncthreads();
  };

  // ---- prologue: x(0) ----
  __syncthreads();
  if (tid < 96) {
    int b = tid/3, cc = tid%3;
    float x = xin[((size_t)(B0+b)*TT)*3 + cc];
    int off = b*ACT_STRIDE + ((2*(CX0 + cc)) ^ ((b&7)<<4));
    *(u16*)(sm + off) = f16b(x);
  }
  __syncthreads();

  float c1 = 0.f, c2 = 0.f, c3 = 0.f, kap0 = 0.f, kap1 = 0.f;

  for (int t = 0; t <= TT + 2; ++t) {
    const int pc = t & 1, pp = pc ^ 1;
    const int xc = pc ? CX1 : CX0;
    const int xp = pp ? CX1 : CX0;
    u32* ring_w = h1ring + (size_t)(t & 7) * HBUF_U32;

    // ======== G1(t) -> h1(t) publish; arrive ========
    if (t < TT) {
      f4v a1[4] = {az, az, az, az};
      #pragma unroll
      for (int i = 0; i < F1; ++i) {
        int c = wv + 4*i;
        if (c < NC1) {
          int cb = (c == 0) ? xc : (c <= 3) ? (CWIN + 32*(c-1)) : (CH1 + 32*(c-4));
          int cb2 = 2*cb;
          s8v x0 = LDA0(cb2), x1 = LDA1(cb2);
          a1[0] = MFMA16(x0, wf1[i][0], a1[0]);
          a1[1] = MFMA16(x1, wf1[i][0], a1[1]);
          a1[2] = MFMA16(x0, wf1[i][1], a1[2]);
          a1[3] = MFMA16(x1, wf1[i][1], a1[3]);
          if (c >= 1) {
            s8v l0, l1;
            if (c <= 3) { int lb2 = 2*(CWINLO + 32*(c-1)); l0 = LDA0(lb2); l1 = LDA1(lb2); }
            else        { int lb2 = 64*(c-4);              l0 = LDL0(lb2); l1 = LDL1(lb2); }
            a1[0] = MFMA16(l0, wf1[i][0], a1[0]);
            a1[1] = MFMA16(l1, wf1[i][0], a1[1]);
            a1[2] = MFMA16(l0, wf1[i][1], a1[2]);
            a1[3] = MFMA16(l1, wf1[i][1], a1[3]);
          }
        }
      }
      WPART(0, a1[0]); WPART(1, a1[1]); WPART(2, a1[2]); WPART(3, a1[3]);
    }
    __syncthreads();
    if (t < TT) LUPD(0, 0, c1, ring_w, h1glo + (size_t)pc * HBUF_U32);
    ARRIVE();

    // ======== barrier shadow: OUT(t-3) entirely from global rings ========
    if (t >= 3 && mem <= 6) {
      const u32* r1 = h1ring + (size_t)((t + 5) & 7) * HBUF_U32;   // h1(t-3)
      const u32* r2 = h2g   + (size_t)((t + 1) & 3) * HBUF_U32;    // h2(t-3)
      const u32* r3 = h3g   + (size_t)((t + 1) & 3) * HBUF_U32;    // h3(t-3)
      f4v ao[4] = {az, az, az, az};
      #pragma unroll
      for (int i = 0; i < FO; ++i) {
        int c = wv + 4*i;
        if (c < NCO) {
          const u32* rp = (c <= 12) ? (r1 + (size_t)c * 16)
                        : (c <= 25) ? (r2 + (size_t)(c - 13) * 16)
                        :             (r3 + (size_t)(c - 26) * 16);
          s8v x0 = RLD(rp, 0), x1 = RLD(rp, 1);
          ao[0] = MFMA16(x0, wfo[0][i], ao[0]);
          ao[1] = MFMA16(x1, wfo[0][i], ao[1]);
          if (mem == 0) {
            ao[2] = MFMA16(x0, wfo[1][i], ao[2]);
            ao[3] = MFMA16(x1, wfo[1][i], ao[3]);
          }
        }
      }
      WPART(4, ao[0]); WPART(5, ao[1]);
      if (mem == 0) { WPART(6, ao[2]); WPART(7, ao[3]); }
      __syncthreads();
      const float* bgs = (const float*)(sm + BGS_OFF);
      const float* bcv = (const float*)(sm + BIASC_OFF);
      int tt = t - 3;
      auto OSUM = [&](int rl, int b) -> float {
        int slot = 4 + ((mem == 0) ? ((rl >> 4)*2) : 0) + (b >> 4);
        float s = bgs[rl];
        #pragma unroll
        for (int w = 0; w < 4; ++w) s += RBF(slot, w, rl & 15, b & 15);
        return s;
      };
      if (mem == 0) {
        if (tid < 32) {
          int b = tid;
          float sc = 1.f + bcv[b];
          float pv[20]; float mx = -3e38f;
          #pragma unroll
          for (int r = 0; r < 20; ++r) { pv[r] = OSUM(r, b) * sc; mx = fmaxf(mx, pv[r]); }
          float den = 0.f;
          #pragma unroll
          for (int r = 0; r < 20; ++r) { pv[r] = __expf(pv[r] - mx); den += pv[r]; }
          float inv = 1.f / den;
          size_t ob = ((size_t)(B0 + b)*TT + tt);
          #pragma unroll
          for (int r = 0; r < 20; ++r) dout[ob*20 + r] = pv[r] * inv;
        }
        for (int idx = tid; idx < 12*32; idx += NTHREADS) {
          int rl = 20 + (idx >> 5), b = idx & 31;
          float v = OSUM(rl, b);
          size_t ob = ((size_t)(B0 + b)*TT + tt);
          dout[OFF_SIG + ob*40 + (rl - 20)] = __expf(v - bcv[b]);
        }
      } else {
        int RB = (mem + 1) * 16;
        for (int idx = tid; idx < 512; idx += NTHREADS) {
          int rl = idx >> 5, b = idx & 31;
          int rc = RB + rl;
          float v = OSUM(rl, b);
          size_t ob = ((size_t)(B0 + b)*TT + tt);
          if (rc < 60)        dout[OFF_SIG + ob*40 + (rc - 20)] = __expf(v - bcv[b]);
          else if (rc < 80)   dout[OFF_RHO + ob*20 + (rc - 60)] = tanhe(v);
          else if (rc < 120)  dout[OFF_MU  + ob*40 + (rc - 80)] = v;
          else if (rc == 120) dout[OFF_ES + ob] = sigm(v);
        }
      }
    }

    // ======== THE one barrier ========
    WAITC((u32)(t + 1) * N_MEM);

    // ---- qA: stage h3(t-2) -> CH3 and h2(t-1) -> CH2 ----
    if (t >= 2 && t <= TT) STAGEH(h3g + (size_t)((t + 2) & 3) * HBUF_U32, CH3);
    if (t >= 1 && t <= TT) STAGEH(h2g + (size_t)((t + 3) & 3) * HBUF_U32, CH2);
    __syncthreads();

    // ---- qB: G3(t-1) MFMA (slots 4-7) ; G2 head into regs ----
    f4v a2[4] = {az, az, az, az};
    if (t >= 1 && t <= TT) {
      f4v a3[4] = {az, az, az, az};
      #pragma unroll
      for (int i = 0; i < F3; ++i) {
        int c = wv + 4*i;
        if (c < NC3) {
          int cb = (c == 0) ? xp
                 : (c <= 13) ? (CH1 + 32*(c-1))
                 : (c <= 26) ? (CH2 + 32*(c-14))
                 : (c <= 29) ? (CWIN + 32*(c-27))
                 : (CH3 + 32*(c-30));
          int cb2 = 2*cb;
          s8v x0 = LDA0(cb2), x1 = LDA1(cb2);
          a3[0] = MFMA16(x0, wf3[i][0], a3[0]);
          a3[1] = MFMA16(x1, wf3[i][0], a3[1]);
          a3[2] = MFMA16(x0, wf3[i][1], a3[2]);
          a3[3] = MFMA16(x1, wf3[i][1], a3[3]);
          if ((c >= 1 && c <= 13) || (c >= 27 && c <= 29)) {
            s8v l0, l1;
            if (c <= 13) { int lb2 = 64*(c-1);               l0 = LDL0(lb2); l1 = LDL1(lb2); }
            else         { int lb2 = 2*(CWINLO + 32*(c-27)); l0 = LDA0(lb2); l1 = LDA1(lb2); }
            a3[0] = MFMA16(l0, wf3[i][0], a3[0]);
            a3[1] = MFMA16(l1, wf3[i][0], a3[1]);
            a3[2] = MFMA16(l0, wf3[i][1], a3[2]);
            a3[3] = MFMA16(l1, wf3[i][1], a3[3]);
          }
        }
      }
      WPART(4, a3[0]); WPART(5, a3[1]); WPART(6, a3[2]); WPART(7, a3[3]);
    }
    if (t < TT) {
      #pragma unroll
      for (int i = 0; i < F2; ++i) {
        int c = wv + 4*i;
        if (c < NC2 && (c == 0 || c >= 17)) {
          int cb = (c == 0) ? xc : (CH2 + 32*(c-17));
          int cb2 = 2*cb;
          s8v x0 = LDA0(cb2), x1 = LDA1(cb2);
          a2[0] = MFMA16(x0, wf2[i][0], a2[0]);
          a2[1] = MFMA16(x1, wf2[i][0], a2[1]);
          a2[2] = MFMA16(x0, wf2[i][1], a2[2]);
          a2[3] = MFMA16(x1, wf2[i][1], a2[3]);
        }
      }
    }
    __syncthreads();

    // ---- qC: stage h1(t)+lo -> CH1/H1LO; stage x(t+1) ----
    if (t < TT) { STAGEH(ring_w, CH1); STAGEHLO(h1glo + (size_t)pc * HBUF_U32); }
    if (t + 1 < TT && tid < 96) {
      int b = tid/3, cc = tid%3;
      float x = xin[((size_t)(B0+b)*TT + (t+1))*3 + cc];
      int off = b*ACT_STRIDE + ((2*(xp + cc)) ^ ((b&7)<<4));
      *(u16*)(sm + off) = f16b(x);
    }
    __syncthreads();

    // ---- qD: attention MFMA (slots 0-3) ; LUPD h3(t-1) -> publish ----
    if (t < TT) {
      f4v aa[4] = {az, az, az, az};
      #pragma unroll
      for (int i = 0; i < FA; ++i) {
        int c = wv + 4*i;
        if (c < NCA) {
          int cb2 = 2*(CH1 + 32*c);
          int lb2 = 64*c;
          s8v x0 = LDA0(cb2), x1 = LDA1(cb2);
          s8v l0 = LDL0(lb2), l1 = LDL1(lb2);
          aa[0] = MFMA16(x0, wfa[i][0], aa[0]);
          aa[1] = MFMA16(x1, wfa[i][0], aa[1]);
          aa[2] = MFMA16(x0, wfa[i][1], aa[2]);
          aa[3] = MFMA16(x1, wfa[i][1], aa[3]);
          aa[0] = MFMA16(l0, wfa[i][0], aa[0]);
          aa[1] = MFMA16(l1, wfa[i][0], aa[1]);
          aa[2] = MFMA16(l0, wfa[i][1], aa[2]);
          aa[3] = MFMA16(l1, wfa[i][1], aa[3]);
          aa[0] = MFMA16(x0, walo[i][0], aa[0]);
          aa[1] = MFMA16(x1, walo[i][0], aa[1]);
          aa[2] = MFMA16(x0, walo[i][1], aa[2]);
          aa[3] = MFMA16(x1, walo[i][1], aa[3]);
        }
      }
      WPART(0, aa[0]); WPART(1, aa[1]); WPART(2, aa[2]); WPART(3, aa[3]);
    }
    if (t >= 1 && t <= TT) LUPD(4, 2, c3, h3g + (size_t)((t + 3) & 3) * HBUF_U32, nullptr);
    __syncthreads();

    if (t < TT) {
      // ---- qE: zero wins + alpha/beta/kappa ----
      float* wins = (float*)(sm + WINS_OFF);
      for (int i = tid; i < 32*80; i += NTHREADS) wins[i] = 0.f;
      float* abk = (float*)(sm + ABK_OFF);
      const float* bas = (const float*)(sm + BAS_OFF);
      #pragma unroll
      for (int half = 0; half < 2; ++half) {
        int idx = tid + half*NTHREADS;
        if (idx < 320) {
          int b = idx & 31, j = idx >> 5;
          float ah = bas[j], bh = bas[10+j], kh = bas[20+j];
          #pragma unroll
          for (int w = 0; w < 4; ++w) {
            ah += RBF(0 + (b>>4), w, j, b & 15);
            if (j < 6) bh += RBF(0 + (b>>4), w, 10 + j, b & 15);
            else       bh += RBF(2 + (b>>4), w, j - 6, b & 15);
            kh += RBF(2 + (b>>4), w, 4 + j, b & 15);
          }
          float& kp = half ? kap1 : kap0;
          kp += __expf(kh);
          abk[0*320 + b*10 + j] = __expf(ah);
          abk[1*320 + b*10 + j] = __expf(bh);
          abk[2*320 + b*10 + j] = kp;
        }
      }
      __syncthreads();

      // ---- qF: phi + one-hot scatter ----
      const unsigned char* chs = (const unsigned char*)(sm + CHAR_OFF);
      const int* lns = (const int*)(sm + LENS_OFF);
      for (int idx = tid; idx < 32*64; idx += NTHREADS) {
        int b = idx >> 6, u = idx & 63;
        if (u < lns[b]) {
          float ph = 0.f, fu = (float)u;
          #pragma unroll
          for (int j = 0; j < 10; ++j) {
            float d = abk[2*320 + b*10 + j] - fu;
            ph += abk[0*320 + b*10 + j] * __expf(-abk[1*320 + b*10 + j]*d*d);
          }
          atomicAdd(&wins[b*80 + (int)chs[b*64 + u]], ph);
        }
      }
      __syncthreads();

      // ---- qG: window -> act (hi + lo) ----
      for (int idx = tid; idx < 32*96; idx += NTHREADS) {
        int b = idx / 96, cc = idx % 96;
        float v = (cc < ALP) ? wins[b*80 + cc] : 0.f;
        u16 hi = f16b(v);
        u16 lo = f16b(v - f2f(hi));
        int sw = (b&7) << 4;
        *(u16*)(sm + b*ACT_STRIDE + ((2*(CWIN + cc)) ^ sw)) = hi;
        *(u16*)(sm + b*ACT_STRIDE + ((2*(CWINLO + cc)) ^ sw)) = lo;
      }
      __syncthreads();

      // ---- qH: G2 tail: h1(t)+lo, win(t)+lo ----
      #pragma unroll
      for (int i = 0; i < F2; ++i) {
        int c = wv + 4*i;
        if (c >= 1 && c <= 16) {
          int cb = (c <= 13) ? (CH1 + 32*(c-1)) : (CWIN + 32*(c-14));
          int cb2 = 2*cb;
          s8v x0 = LDA0(cb2), x1 = LDA1(cb2);
          a2[0] = MFMA16(x0, wf2[i][0], a2[0]);
          a2[1] = MFMA16(x1, wf2[i][0], a2[1]);
          a2[2] = MFMA16(x0, wf2[i][1], a2[2]);
          a2[3] = MFMA16(x1, wf2[i][1], a2[3]);
          s8v l0, l1;
          if (c <= 13) { int lb2 = 64*(c-1);               l0 = LDL0(lb2); l1 = LDL1(lb2); }
          else         { int lb2 = 2*(CWINLO + 32*(c-14)); l0 = LDA0(lb2); l1 = LDA1(lb2); }
          a2[0] = MFMA16(l0, wf2[i][0], a2[0]);
          a2[1] = MFMA16(l1, wf2[i][0], a2[1]);
          a2[2] = MFMA16(l0, wf2[i][1], a2[2]);
          a2[3] = MFMA16(l1, wf2[i][1], a2[3]);
        }
      }
      WPART(0, a2[0]); WPART(1, a2[1]); WPART(2, a2[2]); WPART(3, a2[3]);
      __syncthreads();

      // ---- qI: h2(t) -> publish ----
      LUPD(0, 1, c2, h2g + (size_t)(t & 3) * HBUF_U32, nullptr);
    }
  }
}

extern "C" void kernel_launch(void* const* d_in, const int* in_sizes, int n_in,
                              void* d_out, int out_size, void* d_ws, size_t ws_size,
                              hipStream_t stream) {
  (void)in_sizes; (void)n_in; (void)out_size; (void)ws_size;
  const float* xin  = (const float*)d_in[0];
  const int*   chq  = (const int*)d_in[1];
  const int*   lnq  = (const int*)d_in[2];
  const float* bq   = (const float*)d_in[3];
  const float* Wih1 = (const float*)d_in[4];
  const float* Whh1 = (const float*)d_in[5];
  const float* bih1 = (const float*)d_in[6];
  const float* bhh1 = (const float*)d_in[7];
  const float* Wih2 = (const float*)d_in[8];
  const float* Whh2 = (const float*)d_in[9];
  const float* bih2 = (const float*)d_in[10];
  const float* bhh2 = (const float*)d_in[11];
  const float* Wih3 = (const float*)d_in[12];
  const float* Whh3 = (const float*)d_in[13];
  const float* bih3 = (const float*)d_in[14];
  const float* bhh3 = (const float*)d_in[15];
  const float* Wa   = (const float*)d_in[16];
  const float* ba   = (const float*)d_in[17];
  const float* Wg   = (const float*)d_in[18];
  const float* bg   = (const float*)d_in[19];
  float* dout = (float*)d_out;
  char* ws = (char*)d_ws;
  u32* barr   = (u32*)ws;
  u32* h1ring = (u32*)(ws + 16384);                // 8 x 102400 B
  u32* h2g    = (u32*)(ws + 16384 + 819200);       // 4 x 102400 B
  u32* h3g    = (u32*)(ws + 16384 + 1228800);      // 4 x 102400 B
  u32* h1glo  = (u32*)(ws + 16384 + 1638400);      // 2 x 102400 B

  hipMemsetAsync(ws, 0, 16384, stream);
  hipFuncSetAttribute(reinterpret_cast<const void*>(hwrnn),
                      hipFuncAttributeMaxDynamicSharedMemorySize, LDS_TOTAL);
  hipLaunchKernelGGL(hwrnn, dim3(N_CLUS * N_MEM), dim3(NTHREADS), LDS_TOTAL, stream,
                     xin, chq, lnq, bq, Wih1, Whh1, bih1, bhh1, Wih2, Whh2, bih2, bhh2,
                     Wih3, Whh3, bih3, bhh3, Wa, ba, Wg, bg, dout, barr,
                     h1ring, h2g, h3g, h1glo);
}

// Round 14
// 17315.639 us; speedup vs baseline: 1.3026x; 1.0808x over previous
//
#include <hip/hip_runtime.h>
#include <stdint.h>

typedef short s8v __attribute__((ext_vector_type(8)));
typedef _Float16 h8v __attribute__((ext_vector_type(8)));
typedef float f4v __attribute__((ext_vector_type(4)));
typedef unsigned short u16;
typedef unsigned int u32;
typedef unsigned long long u64;

#define TT 800
#define BB 128
#define UU 64
#define ALP 73
#define DD 400

#define G_BATCH 32
#define N_CLUS 4
#define N_MEM 50
#define NTHREADS 256

// activation columns (f16 elements)
#define CX0 0
#define CX1 32
#define CWIN 64
#define CWINLO 160
#define CH1 256
#define CH2 672
#define CH3 1088
#define ACT_STRIDE 3072

#define NC1 17
#define NC2 30
#define NC3 43
#define NCO 39
#define NCA 13
#define F1 5
#define F2 8
#define F3 11
#define FA 4
#define FO 10

#define ACT_BYTES (32*ACT_STRIDE)          // 98304
#define H1LO_OFF ACT_BYTES                 // 28672
#define H1LO_STRIDE 896
#define RBUF_OFF (H1LO_OFF + 32*H1LO_STRIDE)   // 126976
#define ABK_OFF (RBUF_OFF + 16384)         // slot4 first 3840B
#define WINS_OFF (ABK_OFF + 3840)          // next 10240B (slots 5-7 area)
#define CHAR_OFF (RBUF_OFF + 32768)
#define LENS_OFF (CHAR_OFF + 2048)
#define BIASC_OFF (LENS_OFF + 128)
#define BCI_OFF (BIASC_OFF + 128)
#define BAS_OFF (BCI_OFF + 384)
#define BGS_OFF (BAS_OFF + 128)
#define LDS_TOTAL (BGS_OFF + 128)          // 162688

#define OFF_SIG ((size_t)BB*TT*20)
#define OFF_RHO ((size_t)BB*TT*60)
#define OFF_MU  ((size_t)BB*TT*80)
#define OFF_ES  ((size_t)BB*TT*120)

#define HBUF_U32 25600

#define MFMA16(A,B,C) __builtin_amdgcn_mfma_f32_16x16x32_f16(__builtin_bit_cast(h8v,(A)),__builtin_bit_cast(h8v,(B)),(C),0,0,0)

#define AST(p,v) __hip_atomic_store((p),(v),__ATOMIC_RELAXED,__HIP_MEMORY_SCOPE_AGENT)
#define ALD(p)   __hip_atomic_load((p),__ATOMIC_RELAXED,__HIP_MEMORY_SCOPE_AGENT)

__device__ __forceinline__ u16 f16b(float x) {
  _Float16 h = (_Float16)x;
  return __builtin_bit_cast(u16, h);
}
__device__ __forceinline__ float f2f(u16 h) {
  return (float)__builtin_bit_cast(_Float16, h);
}
__device__ __forceinline__ float sigm(float x) { return 1.f / (1.f + __expf(-x)); }
__device__ __forceinline__ float tanhe(float x) {
  float e = __expf(-2.f * fabsf(x));
  float r = (1.f - e) / (1.f + e);
  return (x < 0.f) ? -r : r;
}
__device__ __forceinline__ int imin(int a, int b) { return a < b ? a : b; }
__device__ __forceinline__ int lstm_row(int mem, int n, int r) {
  return (n*2 + (r>>3))*400 + mem*8 + (r&7);
}
__device__ __forceinline__ int out_orow(int rc) {
  if (rc < 20) return rc;
  if (rc < 60) return 60 + (rc-20);
  if (rc < 80) return 100 + (rc-60);
  if (rc < 120) return 20 + (rc-80);
  if (rc == 120) return 120;
  return -1;
}
__device__ __forceinline__ s8v gath(const float* W, int ld, int grow, int cb, int valid, int k0) {
  union { s8v v; u16 u[8]; } r;
  #pragma unroll
  for (int j = 0; j < 8; ++j) {
    int k = k0 + j;
    float x = 0.f;
    if (grow >= 0 && k < valid) x = W[(size_t)grow * ld + cb + k];
    r.u[j] = f16b(x);
  }
  return r.v;
}
__device__ __forceinline__ s8v gathlo(const float* W, int ld, int grow, int cb, int valid, int k0) {
  union { s8v v; u16 u[8]; } r;
  #pragma unroll
  for (int j = 0; j < 8; ++j) {
    int k = k0 + j;
    float x = 0.f;
    if (grow >= 0 && k < valid) x = W[(size_t)grow * ld + cb + k];
    u16 hi = f16b(x);
    r.u[j] = f16b(x - f2f(hi));
  }
  return r.v;
}

extern "C" __global__ __launch_bounds__(NTHREADS, 1)
void hwrnn(const float* __restrict__ xin, const int* __restrict__ chq,
           const int* __restrict__ lenq, const float* __restrict__ biasq,
           const float* __restrict__ Wih1, const float* __restrict__ Whh1,
           const float* __restrict__ bih1, const float* __restrict__ bhh1,
           const float* __restrict__ Wih2, const float* __restrict__ Whh2,
           const float* __restrict__ bih2, const float* __restrict__ bhh2,
           const float* __restrict__ Wih3, const float* __restrict__ Whh3,
           const float* __restrict__ bih3, const float* __restrict__ bhh3,
           const float* __restrict__ Wa, const float* __restrict__ ba,
           const float* __restrict__ Wg, const float* __restrict__ bg,
           float* __restrict__ dout, u32* __restrict__ barr,
           u32* __restrict__ h1ring, u32* __restrict__ h2g, u32* __restrict__ h3g,
           u32* __restrict__ h1glo)
{
  extern __shared__ __align__(16) char sm[];
  const int tid = threadIdx.x;
  const int wv = tid >> 6;
  const int ln = tid & 63;
  const int cl = blockIdx.x & 3;
  const int mem = blockIdx.x >> 2;
  const int B0 = cl * G_BATCH;

  const int arow = ln & 15;
  const int k0 = (ln >> 4) * 8;
  const int ahi = (ln >> 4) * 16;
  const int axor = (ln & 7) << 4;
  const int rb0 = arow * ACT_STRIDE;
  const int rb1 = (16 + arow) * ACT_STRIDE;
  const int hb0 = H1LO_OFF + arow * H1LO_STRIDE;
  const int hb1 = H1LO_OFF + (16 + arow) * H1LO_STRIDE;
  const f4v az = {0.f, 0.f, 0.f, 0.f};

  // ---- init ----
  for (int i = tid; i * 16 < RBUF_OFF; i += NTHREADS) *(f4v*)(sm + i*16) = az;
  for (int i = tid; i < 32*UU; i += NTHREADS) {
    int b = i >> 6, u = i & 63;
    ((unsigned char*)(sm + CHAR_OFF))[i] = (unsigned char)chq[(B0 + b)*UU + u];
  }
  if (tid < 32) {
    ((int*)(sm + LENS_OFF))[tid] = lenq[B0 + tid];
    ((float*)(sm + BIASC_OFF))[tid] = biasq[B0 + tid];
    ((float*)(sm + BAS_OFF))[tid] = (tid < 30) ? ba[tid] : 0.f;
    float v = 0.f;
    if (mem == 0) { int orow = out_orow(tid); if (orow >= 0) v = bg[orow]; }
    else if (mem >= 1 && mem <= 6 && tid < 16) {
      int orow = out_orow((mem+1)*16 + tid); if (orow >= 0) v = bg[orow];
    }
    ((float*)(sm + BGS_OFF))[tid] = v;
  }
  if (tid < 96) {
    int l = tid >> 5, r = tid & 31;
    int grow = lstm_row(mem, r >> 4, r & 15);
    const float* bi = (l == 0) ? bih1 : (l == 1) ? bih2 : bih3;
    const float* bh = (l == 0) ? bhh1 : (l == 1) ? bhh2 : bhh3;
    ((float*)(sm + BCI_OFF))[l*32 + r] = bi[grow] + bh[grow];
  }

  // ---- stationary weight fragments (f16, VGPR-resident) ----
  s8v wf1[F1][2], wf2[F2][2], wf3[F3][2], wfa[FA][2], walo[FA][2], wfo[2][FO];
  #pragma unroll
  for (int i = 0; i < F1; ++i) {
    int c = wv + 4*i;
    #pragma unroll
    for (int n = 0; n < 2; ++n) {
      s8v v = {0,0,0,0,0,0,0,0};
      if (c < NC1) {
        int grow = lstm_row(mem, n, arow);
        if (c == 0)      v = gath(Wih1, 76, grow, 73, 3, k0);
        else if (c <= 3) v = gath(Wih1, 76, grow, (c-1)*32, imin(32, 73-(c-1)*32), k0);
        else             v = gath(Whh1, 400, grow, (c-4)*32, imin(32, 400-(c-4)*32), k0);
      }
      wf1[i][n] = v;
    }
  }
  #pragma unroll
  for (int i = 0; i < F2; ++i) {
    int c = wv + 4*i;
    #pragma unroll
    for (int n = 0; n < 2; ++n) {
      s8v v = {0,0,0,0,0,0,0,0};
      if (c < NC2) {
        int grow = lstm_row(mem, n, arow);
        if (c == 0)       v = gath(Wih2, 476, grow, 0, 3, k0);
        else if (c <= 13) v = gath(Wih2, 476, grow, 3+32*(c-1), imin(32, 400-32*(c-1)), k0);
        else if (c <= 16) v = gath(Wih2, 476, grow, 403+32*(c-14), imin(32, 73-32*(c-14)), k0);
        else              v = gath(Whh2, 400, grow, 32*(c-17), imin(32, 400-32*(c-17)), k0);
      }
      wf2[i][n] = v;
    }
  }
  #pragma unroll
  for (int i = 0; i < F3; ++i) {
    int c = wv + 4*i;
    #pragma unroll
    for (int n = 0; n < 2; ++n) {
      s8v v = {0,0,0,0,0,0,0,0};
      if (c < NC3) {
        int grow = lstm_row(mem, n, arow);
        if (c == 0)       v = gath(Wih3, 876, grow, 0, 3, k0);
        else if (c <= 13) v = gath(Wih3, 876, grow, 3+32*(c-1), imin(32, 400-32*(c-1)), k0);
        else if (c <= 26) v = gath(Wih3, 876, grow, 403+32*(c-14), imin(32, 400-32*(c-14)), k0);
        else if (c <= 29) v = gath(Wih3, 876, grow, 803+32*(c-27), imin(32, 73-32*(c-27)), k0);
        else              v = gath(Whh3, 400, grow, 32*(c-30), imin(32, 400-32*(c-30)), k0);
      }
      wf3[i][n] = v;
    }
  }
  #pragma unroll
  for (int i = 0; i < FA; ++i) {
    int c = wv + 4*i;
    #pragma unroll
    for (int n = 0; n < 2; ++n) {
      s8v v = {0,0,0,0,0,0,0,0}, vl = v;
      if (c < NCA) {
        int rr = n*16 + arow;
        int grow = (rr < 30) ? rr : -1;
        v  = gath  (Wa, 400, grow, 32*c, imin(32, 400-32*c), k0);
        vl = gathlo(Wa, 400, grow, 32*c, imin(32, 400-32*c), k0);
      }
      wfa[i][n] = v; walo[i][n] = vl;
    }
  }
  #pragma unroll
  for (int o = 0; o < 2; ++o) {
    #pragma unroll
    for (int i = 0; i < FO; ++i) {
      s8v v = {0,0,0,0,0,0,0,0};
      int c = wv + 4*i;
      bool have = (mem == 0) || (mem >= 1 && mem <= 6 && o == 0);
      if (have && c < NCO) {
        int ct = (mem == 0) ? o : (mem + 1);
        int grow = out_orow(ct*16 + arow);
        if (c <= 12)      v = gath(Wg, 1200, grow, 32*c, imin(32, 400-32*c), k0);
        else if (c <= 25) v = gath(Wg, 1200, grow, 400+32*(c-13), imin(32, 400-32*(c-13)), k0);
        else              v = gath(Wg, 1200, grow, 800+32*(c-26), imin(32, 400-32*(c-26)), k0);
      }
      wfo[o][i] = v;
    }
  }

  // ---- helpers ----
  auto LDA0 = [&](int cb2) -> s8v { return *(const s8v*)(sm + rb0 + ((cb2 + ahi) ^ axor)); };
  auto LDA1 = [&](int cb2) -> s8v { return *(const s8v*)(sm + rb1 + ((cb2 + ahi) ^ axor)); };
  auto LDL0 = [&](int cb2) -> s8v { return *(const s8v*)(sm + hb0 + ((cb2 + ahi) ^ axor)); };
  auto LDL1 = [&](int cb2) -> s8v { return *(const s8v*)(sm + hb1 + ((cb2 + ahi) ^ axor)); };
  auto WPART = [&](int slot, f4v a) {
    *(f4v*)(sm + RBUF_OFF + (((slot*4 + wv)*256) + (ln & 15)*16 + (ln >> 4)*4)*4) = a;
  };
  auto RBF = [&](int slot, int w, int col, int row) -> float {
    return ((float*)(sm + RBUF_OFF))[(slot*4 + w)*256 + col*16 + row];
  };
  // OUT A-fragment from global h1 ring (agent-coherent loads)
  auto RLD = [&](const u32* ring, int half) -> s8v {
    union { s8v v; u64 q[2]; } r;
    r.q[0] = ALD((const u64*)ring + ((size_t)(B0 + arow + 16*half)*DD + k0 >> 2));
    r.q[1] = ALD((const u64*)ring + ((size_t)(B0 + arow + 16*half)*DD + k0 + 4 >> 2));
    return r.v;
  };
  const int ub = tid >> 3, uu = tid & 7;
  auto LUPD = [&](int sb, int l, float& c, u32* hg, u32* hlo) {
    int mt = ub >> 4, rw = ub & 15;
    const float* bci = (const float*)(sm + BCI_OFF);
    float vi = bci[l*32 + uu], vf = bci[l*32 + 8 + uu];
    float vg = bci[l*32 + 16 + uu], vo = bci[l*32 + 24 + uu];
    #pragma unroll
    for (int w = 0; w < 4; ++w) {
      vi += RBF(sb + mt, w, uu, rw);
      vf += RBF(sb + mt, w, 8 + uu, rw);
      vg += RBF(sb + 2 + mt, w, uu, rw);
      vo += RBF(sb + 2 + mt, w, 8 + uu, rw);
    }
    c = sigm(vf)*c + sigm(vi)*tanhe(vg);
    float h = sigm(vo)*tanhe(c);
    u16 hb = f16b(h);
    float hl = h - f2f(hb);
    float ho = __shfl_xor(h, 1, 64);
    float hlo_o = __shfl_xor(hl, 1, 64);
    if (!(uu & 1)) {
      size_t gi = ((size_t)(B0 + ub)*DD + mem*8 + uu) >> 1;
      AST(hg + gi, (u32)hb | ((u32)f16b(ho) << 16));
      if (hlo) AST(hlo + gi, (u32)f16b(hl) | ((u32)f16b(hlo_o) << 16));
    }
  };
  // Bulk staging: issue ALL LLC loads into registers, single drain, LDS writes.
  auto STAGEH = [&](const u32* hg, int cbase) {
    u64 va[7], vb[7];
    #pragma unroll
    for (int s = 0; s < 7; ++s) {
      int idx = tid + s*NTHREADS;
      if (idx < 1600) {
        int b = idx / 50, c16 = idx % 50;
        const u64* p = (const u64*)(hg + (((size_t)(B0 + b)*DD + c16*8) >> 1));
        va[s] = ALD(p); vb[s] = ALD(p + 1);
      }
    }
    #pragma unroll
    for (int s = 0; s < 7; ++s) {
      int idx = tid + s*NTHREADS;
      if (idx < 1600) {
        int b = idx / 50, c16 = idx % 50;
        int off = b*ACT_STRIDE + ((2*(cbase + c16*8)) ^ ((b & 7) << 4));
        *(u64*)(sm + off) = va[s];
        *(u64*)(sm + off + 8) = vb[s];
      }
    }
  };
  auto STAGEHLO = [&](const u32* hg) {
    u64 va[7], vb[7];
    #pragma unroll
    for (int s = 0; s < 7; ++s) {
      int idx = tid + s*NTHREADS;
      if (idx < 1600) {
        int b = idx / 50, c16 = idx % 50;
        const u64* p = (const u64*)(hg + (((size_t)(B0 + b)*DD + c16*8) >> 1));
        va[s] = ALD(p); vb[s] = ALD(p + 1);
      }
    }
    #pragma unroll
    for (int s = 0; s < 7; ++s) {
      int idx = tid + s*NTHREADS;
      if (idx < 1600) {
        int b = idx / 50, c16 = idx % 50;
        int off = H1LO_OFF + b*H1LO_STRIDE + ((16*c16) ^ ((b & 7) << 4));
        *(u64*)(sm + off) = va[s];
        *(u64*)(sm + off + 8) = vb[s];
      }
    }
  };
  u32* cA = barr + cl*64;
  auto ARRIVE = [&]() {
    asm volatile("s_waitcnt vmcnt(0)" ::: "memory");
    __syncthreads();
    if (tid == 0) __hip_atomic_fetch_add(cA, 1u, __ATOMIC_RELAXED, __HIP_MEMORY_SCOPE_AGENT);
  };
  auto WAITC = [&](u32 tgt) {
    if (tid == 0) {
      while (ALD(cA) < tgt) __builtin_amdgcn_s_sleep(1);
    }
    __syncthreads();
  };

  // ---- prologue: x(0) ----
  __syncthreads();
  if (tid < 96) {
    int b = tid/3, cc = tid%3;
    float x = xin[((size_t)(B0+b)*TT)*3 + cc];
    int off = b*ACT_STRIDE + ((2*(CX0 + cc)) ^ ((b&7)<<4));
    *(u16*)(sm + off) = f16b(x);
  }
  __syncthreads();

  float c1 = 0.f, c2 = 0.f, c3 = 0.f, kap0 = 0.f, kap1 = 0.f;

  for (int t = 0; t <= TT + 1; ++t) {
    const int pc = t & 1, pp = pc ^ 1;
    const int xc = pc ? CX1 : CX0;
    const int xp = pp ? CX1 : CX0;
    u32* ring_w = h1ring + (size_t)(t & 3) * HBUF_U32;          // h1(t) publish
    const u32* ring_o = h1ring + (size_t)((t + 2) & 3) * HBUF_U32; // h1(t-2) for OUT

    // ======== PRE-WAIT: G1(t) -> h1(t) publish; arrive ========
    if (t < TT) {
      f4v a1[4] = {az, az, az, az};
      #pragma unroll
      for (int i = 0; i < F1; ++i) {
        int c = wv + 4*i;
        if (c < NC1) {
          int cb = (c == 0) ? xc : (c <= 3) ? (CWIN + 32*(c-1)) : (CH1 + 32*(c-4));
          int cb2 = 2*cb;
          s8v x0 = LDA0(cb2), x1 = LDA1(cb2);
          a1[0] = MFMA16(x0, wf1[i][0], a1[0]);
          a1[1] = MFMA16(x1, wf1[i][0], a1[1]);
          a1[2] = MFMA16(x0, wf1[i][1], a1[2]);
          a1[3] = MFMA16(x1, wf1[i][1], a1[3]);
          if (c >= 1) {
            s8v l0, l1;
            if (c <= 3) { int lb2 = 2*(CWINLO + 32*(c-1)); l0 = LDA0(lb2); l1 = LDA1(lb2); }
            else        { int lb2 = 64*(c-4);              l0 = LDL0(lb2); l1 = LDL1(lb2); }
            a1[0] = MFMA16(l0, wf1[i][0], a1[0]);
            a1[1] = MFMA16(l1, wf1[i][0], a1[1]);
            a1[2] = MFMA16(l0, wf1[i][1], a1[2]);
            a1[3] = MFMA16(l1, wf1[i][1], a1[3]);
          }
        }
      }
      WPART(0, a1[0]); WPART(1, a1[1]); WPART(2, a1[2]); WPART(3, a1[3]);
    }
    __syncthreads();
    if (t < TT) LUPD(0, 0, c1, ring_w, h1glo + (size_t)pc * HBUF_U32);
    ARRIVE();

    // ======== THE one barrier ========
    WAITC((u32)(t + 1) * N_MEM);

    // ---- q1: stage h3(t-2) -> CH3 ----
    if (t >= 2) STAGEH(h3g + (size_t)pc * HBUF_U32, CH3);
    __syncthreads();

    // ---- q2: OUT(t-2) MFMA (h1 from ring, h2/h3 from LDS old vintages) ----
    if (t >= 2 && mem <= 6) {
      f4v ao[4] = {az, az, az, az};
      #pragma unroll
      for (int i = 0; i < FO; ++i) {
        int c = wv + 4*i;
        if (c < NCO) {
          s8v x0, x1;
          if (c <= 12) {
            const u32* rp = ring_o + (size_t)c * 16;
            x0 = RLD(rp, 0); x1 = RLD(rp, 1);
          } else {
            int cb = (c <= 25) ? (CH2 + 32*(c-13)) : (CH3 + 32*(c-26));
            x0 = LDA0(2*cb); x1 = LDA1(2*cb);
          }
          ao[0] = MFMA16(x0, wfo[0][i], ao[0]);
          ao[1] = MFMA16(x1, wfo[0][i], ao[1]);
          if (mem == 0) {
            ao[2] = MFMA16(x0, wfo[1][i], ao[2]);
            ao[3] = MFMA16(x1, wfo[1][i], ao[3]);
          }
        }
      }
      WPART(4, ao[0]); WPART(5, ao[1]);
      if (mem == 0) { WPART(6, ao[2]); WPART(7, ao[3]); }
    }
    __syncthreads();

    // ---- q3: stage h2(t-1) -> CH2 ; OUT(t-2) epilogue ----
    if (t >= 1 && t <= TT) STAGEH(h2g + (size_t)pp * HBUF_U32, CH2);
    if (t >= 2 && mem <= 6) {
      const float* bgs = (const float*)(sm + BGS_OFF);
      const float* bcv = (const float*)(sm + BIASC_OFF);
      int tt = t - 2;
      auto OSUM = [&](int rl, int b) -> float {
        int slot = 4 + ((mem == 0) ? ((rl >> 4)*2) : 0) + (b >> 4);
        float s = bgs[rl];
        #pragma unroll
        for (int w = 0; w < 4; ++w) s += RBF(slot, w, rl & 15, b & 15);
        return s;
      };
      if (mem == 0) {
        // wave-parallel pi softmax: 8 threads per batch, 2-3 rows each,
        // shfl_xor max/sum reduce within aligned 8-lane groups
        {
          int b = tid >> 3, r0 = tid & 7;
          float sc = 1.f + bcv[b];
          float pv0 = OSUM(r0, b) * sc;
          float pv1 = OSUM(r0 + 8, b) * sc;
          float pv2 = (r0 < 4) ? OSUM(r0 + 16, b) * sc : -3e38f;
          float mx = fmaxf(fmaxf(pv0, pv1), pv2);
          mx = fmaxf(mx, __shfl_xor(mx, 1, 64));
          mx = fmaxf(mx, __shfl_xor(mx, 2, 64));
          mx = fmaxf(mx, __shfl_xor(mx, 4, 64));
          float e0 = __expf(pv0 - mx), e1 = __expf(pv1 - mx);
          float e2 = (r0 < 4) ? __expf(pv2 - mx) : 0.f;
          float s = e0 + e1 + e2;
          s += __shfl_xor(s, 1, 64);
          s += __shfl_xor(s, 2, 64);
          s += __shfl_xor(s, 4, 64);
          float inv = 1.f / s;
          size_t ob = ((size_t)(B0 + b)*TT + tt);
          dout[ob*20 + r0] = e0 * inv;
          dout[ob*20 + r0 + 8] = e1 * inv;
          if (r0 < 4) dout[ob*20 + r0 + 16] = e2 * inv;
        }
        for (int idx = tid; idx < 12*32; idx += NTHREADS) {
          int rl = 20 + (idx >> 5), b = idx & 31;
          float v = OSUM(rl, b);
          size_t ob = ((size_t)(B0 + b)*TT + tt);
          dout[OFF_SIG + ob*40 + (rl - 20)] = __expf(v - bcv[b]);
        }
      } else {
        int RB = (mem + 1) * 16;
        for (int idx = tid; idx < 512; idx += NTHREADS) {
          int rl = idx >> 5, b = idx & 31;
          int rc = RB + rl;
          float v = OSUM(rl, b);
          size_t ob = ((size_t)(B0 + b)*TT + tt);
          if (rc < 60)        dout[OFF_SIG + ob*40 + (rc - 20)] = __expf(v - bcv[b]);
          else if (rc < 80)   dout[OFF_RHO + ob*20 + (rc - 60)] = tanhe(v);
          else if (rc < 120)  dout[OFF_MU  + ob*40 + (rc - 80)] = v;
          else if (rc == 120) dout[OFF_ES + ob] = sigm(v);
        }
      }
    }
    __syncthreads();

    // ---- q4: G3(t-1) MFMA ; G2 head into regs ----
    f4v a2[4] = {az, az, az, az};
    if (t >= 1 && t <= TT) {
      f4v a3[4] = {az, az, az, az};
      #pragma unroll
      for (int i = 0; i < F3; ++i) {
        int c = wv + 4*i;
        if (c < NC3) {
          int cb = (c == 0) ? xp
                 : (c <= 13) ? (CH1 + 32*(c-1))
                 : (c <= 26) ? (CH2 + 32*(c-14))
                 : (c <= 29) ? (CWIN + 32*(c-27))
                 : (CH3 + 32*(c-30));
          int cb2 = 2*cb;
          s8v x0 = LDA0(cb2), x1 = LDA1(cb2);
          a3[0] = MFMA16(x0, wf3[i][0], a3[0]);
          a3[1] = MFMA16(x1, wf3[i][0], a3[1]);
          a3[2] = MFMA16(x0, wf3[i][1], a3[2]);
          a3[3] = MFMA16(x1, wf3[i][1], a3[3]);
          if ((c >= 1 && c <= 13) || (c >= 27 && c <= 29)) {
            s8v l0, l1;
            if (c <= 13) { int lb2 = 64*(c-1);               l0 = LDL0(lb2); l1 = LDL1(lb2); }
            else         { int lb2 = 2*(CWINLO + 32*(c-27)); l0 = LDA0(lb2); l1 = LDA1(lb2); }
            a3[0] = MFMA16(l0, wf3[i][0], a3[0]);
            a3[1] = MFMA16(l1, wf3[i][0], a3[1]);
            a3[2] = MFMA16(l0, wf3[i][1], a3[2]);
            a3[3] = MFMA16(l1, wf3[i][1], a3[3]);
          }
        }
      }
      WPART(4, a3[0]); WPART(5, a3[1]); WPART(6, a3[2]); WPART(7, a3[3]);
    }
    if (t < TT) {
      #pragma unroll
      for (int i = 0; i < F2; ++i) {
        int c = wv + 4*i;
        if (c < NC2 && (c == 0 || c >= 17)) {
          int cb = (c == 0) ? xc : (CH2 + 32*(c-17));
          int cb2 = 2*cb;
          s8v x0 = LDA0(cb2), x1 = LDA1(cb2);
          a2[0] = MFMA16(x0, wf2[i][0], a2[0]);
          a2[1] = MFMA16(x1, wf2[i][0], a2[1]);
          a2[2] = MFMA16(x0, wf2[i][1], a2[2]);
          a2[3] = MFMA16(x1, wf2[i][1], a2[3]);
        }
      }
    }
    __syncthreads();

    // ---- q5a: stage h1(t)+lo -> CH1/H1LO; stage x(t+1) ----
    if (t < TT) { STAGEH(ring_w, CH1); STAGEHLO(h1glo + (size_t)pc * HBUF_U32); }
    if (t + 1 < TT && tid < 96) {
      int b = tid/3, cc = tid%3;
      float x = xin[((size_t)(B0+b)*TT + (t+1))*3 + cc];
      int off = b*ACT_STRIDE + ((2*(xp + cc)) ^ ((b&7)<<4));
      *(u16*)(sm + off) = f16b(x);
    }
    __syncthreads();

    // ---- q5b: attention MFMA (slots 0-3) ; LUPD h3(t-1) -> publish ----
    if (t < TT) {
      f4v aa[4] = {az, az, az, az};
      #pragma unroll
      for (int i = 0; i < FA; ++i) {
        int c = wv + 4*i;
        if (c < NCA) {
          int cb2 = 2*(CH1 + 32*c);
          int lb2 = 64*c;
          s8v x0 = LDA0(cb2), x1 = LDA1(cb2);
          s8v l0 = LDL0(lb2), l1 = LDL1(lb2);
          aa[0] = MFMA16(x0, wfa[i][0], aa[0]);
          aa[1] = MFMA16(x1, wfa[i][0], aa[1]);
          aa[2] = MFMA16(x0, wfa[i][1], aa[2]);
          aa[3] = MFMA16(x1, wfa[i][1], aa[3]);
          aa[0] = MFMA16(l0, wfa[i][0], aa[0]);
          aa[1] = MFMA16(l1, wfa[i][0], aa[1]);
          aa[2] = MFMA16(l0, wfa[i][1], aa[2]);
          aa[3] = MFMA16(l1, wfa[i][1], aa[3]);
          aa[0] = MFMA16(x0, walo[i][0], aa[0]);
          aa[1] = MFMA16(x1, walo[i][0], aa[1]);
          aa[2] = MFMA16(x0, walo[i][1], aa[2]);
          aa[3] = MFMA16(x1, walo[i][1], aa[3]);
        }
      }
      WPART(0, aa[0]); WPART(1, aa[1]); WPART(2, aa[2]); WPART(3, aa[3]);
    }
    if (t >= 1 && t <= TT) LUPD(4, 2, c3, h3g + (size_t)pp * HBUF_U32, nullptr);
    __syncthreads();

    if (t < TT) {
      // ---- q6: zero wins + alpha/beta/kappa ----
      float* wins = (float*)(sm + WINS_OFF);
      for (int i = tid; i < 32*80; i += NTHREADS) wins[i] = 0.f;
      float* abk = (float*)(sm + ABK_OFF);
      const float* bas = (const float*)(sm + BAS_OFF);
      #pragma unroll
      for (int half = 0; half < 2; ++half) {
        int idx = tid + half*NTHREADS;
        if (idx < 320) {
          int b = idx & 31, j = idx >> 5;
          float ah = bas[j], bh = bas[10+j], kh = bas[20+j];
          #pragma unroll
          for (int w = 0; w < 4; ++w) {
            ah += RBF(0 + (b>>4), w, j, b & 15);
            if (j < 6) bh += RBF(0 + (b>>4), w, 10 + j, b & 15);
            else       bh += RBF(2 + (b>>4), w, j - 6, b & 15);
            kh += RBF(2 + (b>>4), w, 4 + j, b & 15);
          }
          float& kp = half ? kap1 : kap0;
          kp += __expf(kh);
          abk[0*320 + b*10 + j] = __expf(ah);
          abk[1*320 + b*10 + j] = __expf(bh);
          abk[2*320 + b*10 + j] = kp;
        }
      }
      __syncthreads();

      // ---- q7: phi + one-hot scatter ----
      const unsigned char* chs = (const unsigned char*)(sm + CHAR_OFF);
      const int* lns = (const int*)(sm + LENS_OFF);
      for (int idx = tid; idx < 32*64; idx += NTHREADS) {
        int b = idx >> 6, u = idx & 63;
        if (u < lns[b]) {
          float ph = 0.f, fu = (float)u;
          #pragma unroll
          for (int j = 0; j < 10; ++j) {
            float d = abk[2*320 + b*10 + j] - fu;
            ph += abk[0*320 + b*10 + j] * __expf(-abk[1*320 + b*10 + j]*d*d);
          }
          atomicAdd(&wins[b*80 + (int)chs[b*64 + u]], ph);
        }
      }
      __syncthreads();

      // ---- q8: window -> act (hi + lo) ----
      for (int idx = tid; idx < 32*96; idx += NTHREADS) {
        int b = idx / 96, cc = idx % 96;
        float v = (cc < ALP) ? wins[b*80 + cc] : 0.f;
        u16 hi = f16b(v);
        u16 lo = f16b(v - f2f(hi));
        int sw = (b&7) << 4;
        *(u16*)(sm + b*ACT_STRIDE + ((2*(CWIN + cc)) ^ sw)) = hi;
        *(u16*)(sm + b*ACT_STRIDE + ((2*(CWINLO + cc)) ^ sw)) = lo;
      }
      __syncthreads();

      // ---- q9: G2 tail: h1(t)+lo, win(t)+lo ----
      #pragma unroll
      for (int i = 0; i < F2; ++i) {
        int c = wv + 4*i;
        if (c >= 1 && c <= 16) {
          int cb = (c <= 13) ? (CH1 + 32*(c-1)) : (CWIN + 32*(c-14));
          int cb2 = 2*cb;
          s8v x0 = LDA0(cb2), x1 = LDA1(cb2);
          a2[0] = MFMA16(x0, wf2[i][0], a2[0]);
          a2[1] = MFMA16(x1, wf2[i][0], a2[1]);
          a2[2] = MFMA16(x0, wf2[i][1], a2[2]);
          a2[3] = MFMA16(x1, wf2[i][1], a2[3]);
          s8v l0, l1;
          if (c <= 13) { int lb2 = 64*(c-1);               l0 = LDL0(lb2); l1 = LDL1(lb2); }
          else         { int lb2 = 2*(CWINLO + 32*(c-14)); l0 = LDA0(lb2); l1 = LDA1(lb2); }
          a2[0] = MFMA16(l0, wf2[i][0], a2[0]);
          a2[1] = MFMA16(l1, wf2[i][0], a2[1]);
          a2[2] = MFMA16(l0, wf2[i][1], a2[2]);
          a2[3] = MFMA16(l1, wf2[i][1], a2[3]);
        }
      }
      WPART(0, a2[0]); WPART(1, a2[1]); WPART(2, a2[2]); WPART(3, a2[3]);
      __syncthreads();

      // ---- q10: h2(t) -> publish ----
      LUPD(0, 1, c2, h2g + (size_t)pc * HBUF_U32, nullptr);
    }
  }
}

extern "C" void kernel_launch(void* const* d_in, const int* in_sizes, int n_in,
                              void* d_out, int out_size, void* d_ws, size_t ws_size,
                              hipStream_t stream) {
  (void)in_sizes; (void)n_in; (void)out_size; (void)ws_size;
  const float* xin  = (const float*)d_in[0];
  const int*   chq  = (const int*)d_in[1];
  const int*   lnq  = (const int*)d_in[2];
  const float* bq   = (const float*)d_in[3];
  const float* Wih1 = (const float*)d_in[4];
  const float* Whh1 = (const float*)d_in[5];
  const float* bih1 = (const float*)d_in[6];
  const float* bhh1 = (const float*)d_in[7];
  const float* Wih2 = (const float*)d_in[8];
  const float* Whh2 = (const float*)d_in[9];
  const float* bih2 = (const float*)d_in[10];
  const float* bhh2 = (const float*)d_in[11];
  const float* Wih3 = (const float*)d_in[12];
  const float* Whh3 = (const float*)d_in[13];
  const float* bih3 = (const float*)d_in[14];
  const float* bhh3 = (const float*)d_in[15];
  const float* Wa   = (const float*)d_in[16];
  const float* ba   = (const float*)d_in[17];
  const float* Wg   = (const float*)d_in[18];
  const float* bg   = (const float*)d_in[19];
  float* dout = (float*)d_out;
  char* ws = (char*)d_ws;
  u32* barr   = (u32*)ws;
  u32* h1ring = (u32*)(ws + 4096);                    // 4 x 102400 B
  u32* h2g    = (u32*)(ws + 4096 + 409600);           // 2 x 102400 B
  u32* h3g    = (u32*)(ws + 4096 + 409600 + 204800);  // 2 x 102400 B
  u32* h1glo  = (u32*)(ws + 4096 + 409600 + 409600);  // 2 x 102400 B

  hipMemsetAsync(ws, 0, 4096, stream);
  hipFuncSetAttribute(reinterpret_cast<const void*>(hwrnn),
                      hipFuncAttributeMaxDynamicSharedMemorySize, LDS_TOTAL);
  hipLaunchKernelGGL(hwrnn, dim3(N_CLUS * N_MEM), dim3(NTHREADS), LDS_TOTAL, stream,
                     xin, chq, lnq, bq, Wih1, Whh1, bih1, bhh1, Wih2, Whh2, bih2, bhh2,
                     Wih3, Whh3, bih3, bhh3, Wa, ba, Wg, bg, dout, barr,
                     h1ring, h2g, h3g, h1glo);
}